// Round 2
// baseline (1757.100 us; speedup 1.0000x reference)
//
#include <hip/hip_runtime.h>

#define B_ 2
#define T_ 2048
#define D_ 2048
#define H_ 16
#define DK_ 96
#define DV_ 192
#define KEYD 1536
#define VALD 3072
#define NPROJ 9216   // 1536+1536+3072+3072
#define KS_ 4

typedef unsigned short u16;
typedef __bf16 bf16x8 __attribute__((ext_vector_type(8)));
typedef float f32x4 __attribute__((ext_vector_type(4)));

// ---------- helpers ----------
__device__ __forceinline__ u16 f2bf(float f) {          // f32 -> bf16 RNE
  unsigned u = __float_as_uint(f);
  u += 0x7FFF + ((u >> 16) & 1);
  return (u16)(u >> 16);
}
__device__ __forceinline__ float bf2f(u16 v) {
  return __uint_as_float((unsigned)v << 16);
}

__device__ __forceinline__ void gll16(const void* g, void* lds) {
  // async global->LDS, 16B per lane; LDS dest = wave-uniform base + lane*16
  __builtin_amdgcn_global_load_lds(
      (const __attribute__((address_space(1))) void*)g,
      (__attribute__((address_space(3))) void*)lds, 16, 0, 0);
}

// ---------- casts / transposes ----------
__global__ __launch_bounds__(256) void cast_x(const float* __restrict__ in,
                                              u16* __restrict__ out, int n4) {
  int i = blockIdx.x * 256 + threadIdx.x;
  if (i < n4) {
    float4 v = reinterpret_cast<const float4*>(in)[i];
    ushort4 o;
    o.x = f2bf(v.x); o.y = f2bf(v.y); o.z = f2bf(v.z); o.w = f2bf(v.w);
    reinterpret_cast<ushort4*>(out)[i] = o;
  }
}

// src (R,C) fp32 row-major -> dst (C,R) bf16 row-major. Grid (C/32, R/32), 256 thr.
__global__ __launch_bounds__(256) void transpose_cast(const float* __restrict__ src,
                                                      u16* __restrict__ dst, int R, int C) {
  __shared__ float tile[32][33];
  int tx = threadIdx.x & 31, ty = threadIdx.x >> 5;
  int c0 = blockIdx.x * 32, r0 = blockIdx.y * 32;
#pragma unroll
  for (int j = 0; j < 4; ++j)
    tile[ty + j * 8][tx] = src[(size_t)(r0 + ty + j * 8) * C + c0 + tx];
  __syncthreads();
#pragma unroll
  for (int j = 0; j < 4; ++j)
    dst[(size_t)(c0 + ty + j * 8) * R + r0 + tx] = f2bf(tile[tx][ty + j * 8]);
}

// ---------- bf16 MFMA GEMM (m97 structure): C[M,N] = A[M,K] * BT[N,K]^T ----------
template <int OUT_BF16>
__global__ __launch_bounds__(256) void gemm_bt(const u16* __restrict__ A,
                                               const u16* __restrict__ BT,
                                               void* __restrict__ Cv, int M, int N, int K) {
  __shared__ u16 As[128 * 32];
  __shared__ u16 Bs[128 * 32];
  int tid = threadIdx.x;
  int wave = tid >> 6, lane = tid & 63;
  int l15 = lane & 15, l16 = lane >> 4;
  int m0 = blockIdx.y * 128, n0 = blockIdx.x * 128;
  int wm = (wave >> 1) * 64, wn = (wave & 1) * 64;
  f32x4 acc[4][4] = {};
  int nkt = K >> 5;
  for (int kt = 0; kt < nkt; ++kt) {
    int k0 = kt << 5;
    __syncthreads();               // previous tile's reads done
#pragma unroll
    for (int rr = 0; rr < 2; ++rr) {
      int idx = tid + rr * 256;    // 0..511 chunk id, chunk = 16B = 8 bf16
      int row = idx >> 2, kc8 = (idx & 3) * 8;
      unsigned loff = (unsigned)(rr * 256 + wave * 64) * 16;  // wave-uniform
      gll16(A + (size_t)(m0 + row) * K + k0 + kc8, (char*)As + loff);
      gll16(BT + (size_t)(n0 + row) * K + k0 + kc8, (char*)Bs + loff);
    }
    __syncthreads();               // vmcnt(0) drain + barrier
    bf16x8 af[4], bfr[4];
#pragma unroll
    for (int i = 0; i < 4; ++i)
      af[i] = *reinterpret_cast<const bf16x8*>(&As[(wm + i * 16 + l15) * 32 + l16 * 8]);
#pragma unroll
    for (int i = 0; i < 4; ++i)
      bfr[i] = *reinterpret_cast<const bf16x8*>(&Bs[(wn + i * 16 + l15) * 32 + l16 * 8]);
#pragma unroll
    for (int mi = 0; mi < 4; ++mi)
#pragma unroll
      for (int ni = 0; ni < 4; ++ni)
        acc[mi][ni] = __builtin_amdgcn_mfma_f32_16x16x32_bf16(af[mi], bfr[ni], acc[mi][ni], 0, 0, 0);
  }
  // D layout: col = lane&15, row = (lane>>4)*4 + j   [m89-verified]
#pragma unroll
  for (int mi = 0; mi < 4; ++mi)
#pragma unroll
    for (int ni = 0; ni < 4; ++ni)
#pragma unroll
      for (int j = 0; j < 4; ++j) {
        int row = m0 + wm + mi * 16 + l16 * 4 + j;
        int col = n0 + wn + ni * 16 + l15;
        if (OUT_BF16)
          ((u16*)Cv)[(size_t)row * N + col] = f2bf(acc[mi][ni][j]);
        else
          ((float*)Cv)[(size_t)row * N + col] = acc[mi][ni][j];
      }
}

// ---------- beta / g projections (N=16 each), fp32 ----------
__global__ __launch_bounds__(256) void proj_bg(const float* __restrict__ x,
    const float* __restrict__ Wb, const float* __restrict__ Wa,
    const float* __restrict__ A_log, const float* __restrict__ dt_bias,
    float* __restrict__ beta, float* __restrict__ gg) {
  __shared__ float xs[4 * 2048];
  __shared__ float red[4][32][8];
  int tid = threadIdx.x;
  int r0 = blockIdx.x * 4;
  for (int i = tid; i < 4 * 2048; i += 256)
    xs[i] = x[(size_t)r0 * D_ + i];
  __syncthreads();
  int colg = tid & 31, ks = tid >> 5;      // 32 cols x 8 k-slices
  const float* W = (colg < 16) ? Wb : Wa;
  int wc = colg & 15;
  float p0 = 0, p1 = 0, p2 = 0, p3 = 0;
  int kbeg = ks * 256;
  for (int k = kbeg; k < kbeg + 256; ++k) {
    float wv = W[k * H_ + wc];
    p0 += xs[k] * wv;
    p1 += xs[2048 + k] * wv;
    p2 += xs[4096 + k] * wv;
    p3 += xs[6144 + k] * wv;
  }
  red[0][colg][ks] = p0; red[1][colg][ks] = p1;
  red[2][colg][ks] = p2; red[3][colg][ks] = p3;
  __syncthreads();
  if (tid < 128) {
    int row = tid >> 5, col = tid & 31;
    float d = 0;
#pragma unroll
    for (int i = 0; i < 8; ++i) d += red[row][col][i];
    int r = r0 + row;
    if (col < 16) {
      beta[(size_t)r * H_ + col] = 1.f / (1.f + __expf(-d));
    } else {
      int hh = col - 16;
      float z = d + dt_bias[hh];
      float sp = (z > 20.f) ? z : log1pf(__expf(z));
      gg[(size_t)r * H_ + hh] = -__expf(A_log[hh]) * sp;
    }
  }
}

// ---------- conv(KS=4)+SiLU+per-head L2 norm for q,k (bf16 in/out) ----------
__global__ __launch_bounds__(256) void conv_qk(const u16* __restrict__ P,
    const float* __restrict__ wq, const float* __restrict__ wk,
    u16* __restrict__ qc, u16* __restrict__ kc) {
  int bt = blockIdx.x;
  int t = bt & (T_ - 1);
  int tid = threadIdx.x, h = tid >> 4, li = tid & 15;
#pragma unroll
  for (int part = 0; part < 2; ++part) {
    const float* w = part ? wk : wq;
    const u16* base = P + (size_t)bt * NPROJ + part * KEYD + h * DK_;
    float y[6]; float ss = 0.f;
#pragma unroll
    for (int jj = 0; jj < 6; ++jj) {
      int c = li + jj * 16;
      int ch = h * DK_ + c;
      float a = 0.f;
#pragma unroll
      for (int j = 0; j < KS_; ++j) {
        int dt = j - (KS_ - 1);
        if (t + dt >= 0) a += bf2f(base[(ptrdiff_t)dt * NPROJ + c]) * w[ch * KS_ + j];
      }
      float yv = a / (1.f + __expf(-a));     // silu
      y[jj] = yv; ss += yv * yv;
    }
    ss += __shfl_xor(ss, 1); ss += __shfl_xor(ss, 2);
    ss += __shfl_xor(ss, 4); ss += __shfl_xor(ss, 8);
    float rn = rsqrtf(ss + 1e-12f);
    u16* out = (part ? kc : qc) + (size_t)bt * KEYD + h * DK_;
#pragma unroll
    for (int jj = 0; jj < 6; ++jj) out[li + jj * 16] = f2bf(y[jj] * rn);
  }
}

// ---------- conv(KS=4)+SiLU for v (bf16 in/out) ----------
__global__ __launch_bounds__(256) void conv_v(const u16* __restrict__ P,
    const float* __restrict__ wv, u16* __restrict__ vc) {
  int id = blockIdx.x * 256 + threadIdx.x;   // bt*3072 + c, exact grid
  int bt = id / VALD, c = id - bt * VALD;
  int t = bt & (T_ - 1);
  const u16* base = P + (size_t)bt * NPROJ + 2 * KEYD + c;
  float a = 0.f;
#pragma unroll
  for (int j = 0; j < KS_; ++j) {
    int dt = j - (KS_ - 1);
    if (t + dt >= 0) a += bf2f(base[(ptrdiff_t)dt * NPROJ]) * wv[c * KS_ + j];
  }
  vc[id] = f2bf(a / (1.f + __expf(-a)));
}

// ---------- gated delta scan (bf16 q/k/v in, bf16 o out, f32 state) ----------
// S columns are independent: block = (b,h,vblock of 64 cols), thread = (col, k-quarter).
__global__ __launch_bounds__(256) void scan(const u16* __restrict__ qc,
    const u16* __restrict__ kc, const u16* __restrict__ vc,
    const float* __restrict__ gg, const float* __restrict__ bb,
    u16* __restrict__ o) {
  int bid = blockIdx.x;           // 96 = B*H*3
  int vb = bid % 3, bh = bid / 3;
  int h = bh & 15, b = bh >> 4;
  int tid = threadIdx.x, vq = tid & 3, vl = tid >> 2;
  int col = vb * 64 + vl;
  const u16* kp = kc + (size_t)b * T_ * KEYD + h * DK_ + vq * 24;
  const u16* qp = qc + (size_t)b * T_ * KEYD + h * DK_ + vq * 24;
  const u16* vp = vc + (size_t)b * T_ * VALD + h * DV_ + col;
  const float* gp = gg + (size_t)b * T_ * H_ + h;
  const float* bp = bb + (size_t)b * T_ * H_ + h;
  u16* op = o + (size_t)b * T_ * VALD + h * DV_ + col;
  float s[24];
#pragma unroll
  for (int j = 0; j < 24; ++j) s[j] = 0.f;

  float kA[24], qA[24], kB[24], qB[24];
  float vA, gA, bA, vB, gB, bB;

#define UNPACK8(U, dst, base) { \
    dst[base+0] = __uint_as_float((U).x << 16); \
    dst[base+1] = __uint_as_float((U).x & 0xFFFF0000u); \
    dst[base+2] = __uint_as_float((U).y << 16); \
    dst[base+3] = __uint_as_float((U).y & 0xFFFF0000u); \
    dst[base+4] = __uint_as_float((U).z << 16); \
    dst[base+5] = __uint_as_float((U).z & 0xFFFF0000u); \
    dst[base+6] = __uint_as_float((U).w << 16); \
    dst[base+7] = __uint_as_float((U).w & 0xFFFF0000u); \
  }

#define LOADT(tt, Kv, Qv, Vv, Gv, Bv) { \
    const uint4* kq_ = reinterpret_cast<const uint4*>(kp + (size_t)(tt) * KEYD); \
    const uint4* qq_ = reinterpret_cast<const uint4*>(qp + (size_t)(tt) * KEYD); \
    uint4 u0 = kq_[0], u1 = kq_[1], u2 = kq_[2]; \
    uint4 w0 = qq_[0], w1 = qq_[1], w2 = qq_[2]; \
    UNPACK8(u0, Kv, 0); UNPACK8(u1, Kv, 8); UNPACK8(u2, Kv, 16); \
    UNPACK8(w0, Qv, 0); UNPACK8(w1, Qv, 8); UNPACK8(w2, Qv, 16); \
    Vv = bf2f(vp[(size_t)(tt) * VALD]); \
    Gv = gp[(size_t)(tt) * H_]; \
    Bv = bp[(size_t)(tt) * H_]; \
  }

#define STEPT(tt, Kv, Qv, Vv, Gv, Bv) { \
    float alpha = __expf(Gv); \
    float r_ = 0.f; \
    _Pragma("unroll") \
    for (int j = 0; j < 24; ++j) r_ += Kv[j] * s[j]; \
    r_ += __shfl_xor(r_, 1); r_ += __shfl_xor(r_, 2); \
    float sc = Bv * (Vv - r_); \
    float od = 0.f; \
    _Pragma("unroll") \
    for (int j = 0; j < 24; ++j) { s[j] = alpha * s[j] + sc * Kv[j]; od += Qv[j] * s[j]; } \
    od += __shfl_xor(od, 1); od += __shfl_xor(od, 2); \
    if (vq == 0) op[(size_t)(tt) * VALD] = f2bf(od); \
  }

  LOADT(0, kA, qA, vA, gA, bA);
  for (int t = 0; t < T_; t += 2) {
    LOADT(t + 1, kB, qB, vB, gB, bB);
    STEPT(t, kA, qA, vA, gA, bA);
    if (t + 2 < T_) LOADT(t + 2, kA, qA, vA, gA, bA);
    STEPT(t + 1, kB, qB, vB, gB, bB);
  }
#undef LOADT
#undef STEPT
#undef UNPACK8
}

// ---------- gated RMSNorm over DV per head -> bf16 ----------
__global__ __launch_bounds__(256) void rmsnorm_gate(const u16* __restrict__ o,
    const u16* __restrict__ P, const float* __restrict__ w, u16* __restrict__ onb) {
  int bt = blockIdx.x;
  int tid = threadIdx.x, h = tid >> 4, li = tid & 15;
  const u16* orow = o + (size_t)bt * VALD + h * DV_;
  const u16* grow = P + (size_t)bt * NPROJ + 2 * KEYD + VALD + h * DV_;  // g-proj cols
  float y[12]; float ss = 0.f;
#pragma unroll
  for (int jj = 0; jj < 12; ++jj) {
    float v = bf2f(orow[li + jj * 16]);
    y[jj] = v; ss += v * v;
  }
  ss += __shfl_xor(ss, 1); ss += __shfl_xor(ss, 2);
  ss += __shfl_xor(ss, 4); ss += __shfl_xor(ss, 8);
  float rms = rsqrtf(ss * (1.f / DV_) + 1e-6f);
  u16* out = onb + (size_t)bt * VALD + h * DV_;
#pragma unroll
  for (int jj = 0; jj < 12; ++jj) {
    int c = li + jj * 16;
    float gv = bf2f(grow[c]);
    float sig = 1.f / (1.f + __expf(-gv));
    out[c] = f2bf(y[jj] * rms * w[c] * sig);
  }
}

// ---------- launch ----------
extern "C" void kernel_launch(void* const* d_in, const int* in_sizes, int n_in,
                              void* d_out, int out_size, void* d_ws, size_t ws_size,
                              hipStream_t stream) {
  (void)in_sizes; (void)n_in; (void)out_size; (void)ws_size;
  const float* x      = (const float*)d_in[0];
  const float* Wq     = (const float*)d_in[1];
  const float* Wk     = (const float*)d_in[2];
  const float* Wv     = (const float*)d_in[3];
  const float* Wb     = (const float*)d_in[4];
  const float* Wa     = (const float*)d_in[5];
  const float* Wg     = (const float*)d_in[6];
  const float* Wo     = (const float*)d_in[7];
  const float* cqw    = (const float*)d_in[8];
  const float* ckw    = (const float*)d_in[9];
  const float* cvw    = (const float*)d_in[10];
  const float* A_log  = (const float*)d_in[11];
  const float* dt_bias= (const float*)d_in[12];
  const float* onw    = (const float*)d_in[13];
  float* out = (float*)d_out;

  char* ws = (char*)d_ws;
  // Liveness-aliased layout (total 155,713,536 B ≈ 149 MB):
  //  [0, 54.5MB)   : xb+WT (gemm1 inputs)  ->  qc/kc/vc (bf16)  ->  onb (bf16)
  //  [54.5,130MB)  : P (bf16, gemm1 out)   ->  WoT (bf16, transposed late)
  //  [130,130.5MB) : beta, gg (f32)
  //  [130.5,155.7) : osc (bf16 scan out)
  u16*   xb   = (u16*)  (ws + 0);            // 16,777,216
  u16*   WT   = (u16*)  (ws + 16777216);     // 37,748,736
  u16*   qc   = (u16*)  (ws + 0);            // 12,582,912 (alias, after gemm1)
  u16*   kc   = (u16*)  (ws + 12582912);     // 12,582,912 (alias)
  u16*   vc   = (u16*)  (ws + 25165824);     // 25,165,824 (alias)
  u16*   onb  = (u16*)  (ws + 0);            // 25,165,824 (alias, after scan)
  u16*   P    = (u16*)  (ws + 54525952);     // 75,497,472
  u16*   WoT  = (u16*)  (ws + 54525952);     // 12,582,912 (alias, after rmsnorm)
  float* beta = (float*)(ws + 130023424);    // 262,144
  float* gg   = (float*)(ws + 130285568);    // 262,144
  u16*   osc  = (u16*)  (ws + 130547712);    // 25,165,824  -> end 155,713,536

  int n4 = B_ * T_ * D_ / 4;
  cast_x<<<(n4 + 255) / 256, 256, 0, stream>>>(x, xb, n4);
  transpose_cast<<<dim3(48, 64), 256, 0, stream>>>(Wq, WT, 2048, 1536);
  transpose_cast<<<dim3(48, 64), 256, 0, stream>>>(Wk, WT + (size_t)1536 * 2048, 2048, 1536);
  transpose_cast<<<dim3(96, 64), 256, 0, stream>>>(Wv, WT + (size_t)3072 * 2048, 2048, 3072);
  transpose_cast<<<dim3(96, 64), 256, 0, stream>>>(Wg, WT + (size_t)6144 * 2048, 2048, 3072);

  gemm_bt<1><<<dim3(NPROJ / 128, (B_ * T_) / 128), 256, 0, stream>>>(xb, WT, P, B_ * T_, NPROJ, D_);
  proj_bg<<<(B_ * T_) / 4, 256, 0, stream>>>(x, Wb, Wa, A_log, dt_bias, beta, gg);
  conv_qk<<<B_ * T_, 256, 0, stream>>>(P, cqw, ckw, qc, kc);
  conv_v<<<(B_ * T_ * VALD) / 256, 256, 0, stream>>>(P, cvw, vc);
  scan<<<B_ * H_ * 3, 256, 0, stream>>>(qc, kc, vc, gg, beta, osc);
  rmsnorm_gate<<<B_ * T_, 256, 0, stream>>>(osc, P, onw, onb);
  transpose_cast<<<dim3(64, 96), 256, 0, stream>>>(Wo, WoT, 3072, 2048);
  gemm_bt<0><<<dim3(D_ / 128, (B_ * T_) / 128), 256, 0, stream>>>(onb, WoT, out, B_ * T_, D_, VALD);
}

// Round 3
// 1407.590 us; speedup vs baseline: 1.2483x; 1.2483x over previous
//
#include <hip/hip_runtime.h>

#define B_ 2
#define T_ 2048
#define D_ 2048
#define H_ 16
#define DK_ 96
#define DV_ 192
#define KEYD 1536
#define VALD 3072
#define NPROJ 9216
#define PQK 6144     // Pqkv row width (q|k|v)
#define KS_ 4
#define C_ 64
#define NC_ 32       // T_/C_

typedef unsigned short u16;
typedef unsigned int u32;
typedef __bf16 bf16x8 __attribute__((ext_vector_type(8)));
typedef float f32x4 __attribute__((ext_vector_type(4)));

// ---------- helpers ----------
__device__ __forceinline__ u16 f2bf(float f) {
  unsigned u = __float_as_uint(f);
  u += 0x7FFF + ((u >> 16) & 1);
  return (u16)(u >> 16);
}
__device__ __forceinline__ float bf2f(u16 v) { return __uint_as_float((unsigned)v << 16); }
__device__ __forceinline__ float bflo(u32 w) { return __uint_as_float(w << 16); }
__device__ __forceinline__ float bfhi(u32 w) { return __uint_as_float(w & 0xFFFF0000u); }
__device__ __forceinline__ void up8(uint4 u, float* f) {
  f[0]=bflo(u.x); f[1]=bfhi(u.x); f[2]=bflo(u.y); f[3]=bfhi(u.y);
  f[4]=bflo(u.z); f[5]=bfhi(u.z); f[6]=bflo(u.w); f[7]=bfhi(u.w);
}

__device__ __forceinline__ void gll16(const void* g, void* lds) {
  __builtin_amdgcn_global_load_lds(
      (const __attribute__((address_space(1))) void*)g,
      (__attribute__((address_space(3))) void*)lds, 16, 0, 0);
}

// ---------- casts / transposes ----------
__global__ __launch_bounds__(256) void cast_x(const float* __restrict__ in,
                                              u16* __restrict__ out, int n4) {
  int i = blockIdx.x * 256 + threadIdx.x;
  if (i < n4) {
    float4 v = reinterpret_cast<const float4*>(in)[i];
    ushort4 o;
    o.x = f2bf(v.x); o.y = f2bf(v.y); o.z = f2bf(v.z); o.w = f2bf(v.w);
    reinterpret_cast<ushort4*>(out)[i] = o;
  }
}

__global__ __launch_bounds__(256) void transpose_cast(const float* __restrict__ src,
                                                      u16* __restrict__ dst, int R, int C) {
  __shared__ float tile[32][33];
  int tx = threadIdx.x & 31, ty = threadIdx.x >> 5;
  int c0 = blockIdx.x * 32, r0 = blockIdx.y * 32;
#pragma unroll
  for (int j = 0; j < 4; ++j)
    tile[ty + j * 8][tx] = src[(size_t)(r0 + ty + j * 8) * C + c0 + tx];
  __syncthreads();
#pragma unroll
  for (int j = 0; j < 4; ++j)
    dst[(size_t)(c0 + ty + j * 8) * R + r0 + tx] = f2bf(tile[tx][ty + j * 8]);
}

// ---------- bf16 MFMA GEMM: C = A[M,K] * BT[N,K]^T ----------
// OUT16=1: split bf16 output (col<nsplit -> C0 stride s0, else C1 stride s1). OUT16=0: f32.
template <int OUT16>
__global__ __launch_bounds__(256) void gemm_bt(const u16* __restrict__ A,
                                               const u16* __restrict__ BT,
                                               u16* __restrict__ C0, u16* __restrict__ C1,
                                               float* __restrict__ Cf,
                                               int M, int N, int K, int nsplit, int s0, int s1) {
  __shared__ u16 As[128 * 32];
  __shared__ u16 Bs[128 * 32];
  int tid = threadIdx.x;
  int wave = tid >> 6, lane = tid & 63;
  int l15 = lane & 15, l16 = lane >> 4;
  int m0 = blockIdx.y * 128, n0 = blockIdx.x * 128;
  int wm = (wave >> 1) * 64, wn = (wave & 1) * 64;
  f32x4 acc[4][4] = {};
  int nkt = K >> 5;
  for (int kt = 0; kt < nkt; ++kt) {
    int k0 = kt << 5;
    __syncthreads();
#pragma unroll
    for (int rr = 0; rr < 2; ++rr) {
      int idx = tid + rr * 256;
      int row = idx >> 2, kc8 = (idx & 3) * 8;
      unsigned loff = (unsigned)(rr * 256 + wave * 64) * 16;
      gll16(A + (size_t)(m0 + row) * K + k0 + kc8, (char*)As + loff);
      gll16(BT + (size_t)(n0 + row) * K + k0 + kc8, (char*)Bs + loff);
    }
    __syncthreads();
    bf16x8 af[4], bfr[4];
#pragma unroll
    for (int i = 0; i < 4; ++i)
      af[i] = *reinterpret_cast<const bf16x8*>(&As[(wm + i * 16 + l15) * 32 + l16 * 8]);
#pragma unroll
    for (int i = 0; i < 4; ++i)
      bfr[i] = *reinterpret_cast<const bf16x8*>(&Bs[(wn + i * 16 + l15) * 32 + l16 * 8]);
#pragma unroll
    for (int mi = 0; mi < 4; ++mi)
#pragma unroll
      for (int ni = 0; ni < 4; ++ni)
        acc[mi][ni] = __builtin_amdgcn_mfma_f32_16x16x32_bf16(af[mi], bfr[ni], acc[mi][ni], 0, 0, 0);
  }
#pragma unroll
  for (int mi = 0; mi < 4; ++mi)
#pragma unroll
    for (int ni = 0; ni < 4; ++ni)
#pragma unroll
      for (int j = 0; j < 4; ++j) {
        int row = m0 + wm + mi * 16 + l16 * 4 + j;
        int col = n0 + wn + ni * 16 + l15;
        if (OUT16) {
          if (col < nsplit) C0[(size_t)row * s0 + col] = f2bf(acc[mi][ni][j]);
          else              C1[(size_t)row * s1 + col - nsplit] = f2bf(acc[mi][ni][j]);
        } else {
          Cf[(size_t)row * N + col] = acc[mi][ni][j];
        }
      }
}

// ---------- beta / g projections ----------
__global__ __launch_bounds__(256) void proj_bg(const float* __restrict__ x,
    const float* __restrict__ Wb, const float* __restrict__ Wa,
    const float* __restrict__ A_log, const float* __restrict__ dt_bias,
    float* __restrict__ beta, float* __restrict__ gg) {
  __shared__ float xs[4 * 2048];
  __shared__ float red[4][32][8];
  int tid = threadIdx.x;
  int r0 = blockIdx.x * 4;
  for (int i = tid; i < 4 * 2048; i += 256)
    xs[i] = x[(size_t)r0 * D_ + i];
  __syncthreads();
  int colg = tid & 31, ks = tid >> 5;
  const float* W = (colg < 16) ? Wb : Wa;
  int wc = colg & 15;
  float p0 = 0, p1 = 0, p2 = 0, p3 = 0;
  int kbeg = ks * 256;
  for (int k = kbeg; k < kbeg + 256; ++k) {
    float wv = W[k * H_ + wc];
    p0 += xs[k] * wv;
    p1 += xs[2048 + k] * wv;
    p2 += xs[4096 + k] * wv;
    p3 += xs[6144 + k] * wv;
  }
  red[0][colg][ks] = p0; red[1][colg][ks] = p1;
  red[2][colg][ks] = p2; red[3][colg][ks] = p3;
  __syncthreads();
  if (tid < 128) {
    int row = tid >> 5, col = tid & 31;
    float d = 0;
#pragma unroll
    for (int i = 0; i < 8; ++i) d += red[row][col][i];
    int r = r0 + row;
    if (col < 16) {
      beta[(size_t)r * H_ + col] = 1.f / (1.f + __expf(-d));
    } else {
      int hh = col - 16;
      float z = d + dt_bias[hh];
      float sp = (z > 20.f) ? z : log1pf(__expf(z));
      gg[(size_t)r * H_ + hh] = -__expf(A_log[hh]) * sp;
    }
  }
}

// ---------- conv(KS=4)+SiLU+L2norm for q,k ----------
__global__ __launch_bounds__(256) void conv_qk(const u16* __restrict__ Pqkv,
    const float* __restrict__ wq, const float* __restrict__ wk,
    u16* __restrict__ qc, u16* __restrict__ kc) {
  int bt = blockIdx.x;
  int t = bt & (T_ - 1);
  int tid = threadIdx.x, h = tid >> 4, li = tid & 15;
#pragma unroll
  for (int part = 0; part < 2; ++part) {
    const float* w = part ? wk : wq;
    const u16* base = Pqkv + (size_t)bt * PQK + part * KEYD + h * DK_;
    float y[6]; float ss = 0.f;
#pragma unroll
    for (int jj = 0; jj < 6; ++jj) {
      int c = li + jj * 16;
      int ch = h * DK_ + c;
      float a = 0.f;
#pragma unroll
      for (int j = 0; j < KS_; ++j) {
        int dt = j - (KS_ - 1);
        if (t + dt >= 0) a += bf2f(base[(ptrdiff_t)dt * PQK + c]) * w[ch * KS_ + j];
      }
      float yv = a / (1.f + __expf(-a));
      y[jj] = yv; ss += yv * yv;
    }
    ss += __shfl_xor(ss, 1); ss += __shfl_xor(ss, 2);
    ss += __shfl_xor(ss, 4); ss += __shfl_xor(ss, 8);
    float rn = rsqrtf(ss + 1e-12f);
    u16* out = (part ? kc : qc) + (size_t)bt * KEYD + h * DK_;
#pragma unroll
    for (int jj = 0; jj < 6; ++jj) out[li + jj * 16] = f2bf(y[jj] * rn);
  }
}

// ---------- conv(KS=4)+SiLU for v ----------
__global__ __launch_bounds__(256) void conv_v(const u16* __restrict__ Pqkv,
    const float* __restrict__ wv, u16* __restrict__ vc) {
  int id = blockIdx.x * 256 + threadIdx.x;
  int bt = id / VALD, c = id - bt * VALD;
  int t = bt & (T_ - 1);
  const u16* base = Pqkv + (size_t)bt * PQK + 2 * KEYD + c;
  float a = 0.f;
#pragma unroll
  for (int j = 0; j < KS_; ++j) {
    int dt = j - (KS_ - 1);
    if (t + dt >= 0) a += bf2f(base[(ptrdiff_t)dt * PQK]) * wv[c * KS_ + j];
  }
  vc[id] = f2bf(a / (1.f + __expf(-a)));
}

// ================= chunked gated-delta scan =================
// prep: per (b,h,chunk): A = tril(exp(Gp_t-Gc_j) beta_j k_j.k_t); U=(I+A)^-1 V (in place
// over vc); W=(I+A)^-1 diag(Dp)K. Also Gcum, cd_t = beta_t exp(Gc63-Gc_t), lam = exp(Gc63).
__global__ __launch_bounds__(320) void chunk_prep(
    const u16* __restrict__ kc, u16* __restrict__ Uv /* = vc, in-place */,
    const float* __restrict__ gg, const float* __restrict__ beta,
    u16* __restrict__ Wg, float* __restrict__ Gcum,
    float* __restrict__ cdArr, float* __restrict__ lamArr) {
  __shared__ u16 ktL[64 * 104];      // padded rows
  __shared__ float AmL[64 * 68];     // padded rows
  __shared__ float glL[64], GclL[64], blL[64], DplL[64];
  int tid = threadIdx.x;
  int flat = blockIdx.x;
  int c = flat & 31, bh = flat >> 5, h = bh & 15, b = bh >> 4;
  int bT0 = b * T_ + c * 64;

  // stage k tile (96 u16 per row -> 48 u32)
  {
    const u32* kg = (const u32*)(kc + (size_t)bT0 * KEYD + h * DK_);
    for (int i = tid; i < 3072; i += 320) {
      int t = i / 48, dd = i - t * 48;
      ((u32*)ktL)[t * 52 + dd] = kg[(size_t)t * (KEYD / 2) + dd];
    }
  }
  if (tid < 64) {
    float g = gg[(size_t)(bT0 + tid) * H_ + h];
    float bv = beta[(size_t)(bT0 + tid) * H_ + h];
    float v = g;
#pragma unroll
    for (int off = 1; off < 64; off <<= 1) {
      float u = __shfl_up(v, off);
      if (tid >= off) v += u;
    }
    float g63 = __shfl(v, 63);
    glL[tid] = g; GclL[tid] = v; blL[tid] = bv; DplL[tid] = __expf(v - g);
    Gcum[(size_t)flat * 64 + tid] = v;
    cdArr[(size_t)flat * 64 + tid] = bv * __expf(g63 - v);
    if (tid == 63) lamArr[flat] = __expf(v);
  }
  __syncthreads();

  // A matrix (4x4 sub-blocks per thread, tid<256)
  if (tid < 256) {
    int tb = (tid >> 4) << 2, jb = (tid & 15) << 2;
    float a44[16];
#pragma unroll
    for (int i = 0; i < 16; ++i) a44[i] = 0.f;
    if (jb <= tb) {
#pragma unroll
      for (int dd8 = 0; dd8 < 12; ++dd8) {
        uint4 kr0 = *(const uint4*)((const char*)ktL + (tb + 0) * 208 + dd8 * 16);
        uint4 kr1 = *(const uint4*)((const char*)ktL + (tb + 1) * 208 + dd8 * 16);
        uint4 kr2 = *(const uint4*)((const char*)ktL + (tb + 2) * 208 + dd8 * 16);
        uint4 kr3 = *(const uint4*)((const char*)ktL + (tb + 3) * 208 + dd8 * 16);
        uint4 jr0 = *(const uint4*)((const char*)ktL + (jb + 0) * 208 + dd8 * 16);
        uint4 jr1 = *(const uint4*)((const char*)ktL + (jb + 1) * 208 + dd8 * 16);
        uint4 jr2 = *(const uint4*)((const char*)ktL + (jb + 2) * 208 + dd8 * 16);
        uint4 jr3 = *(const uint4*)((const char*)ktL + (jb + 3) * 208 + dd8 * 16);
        float kf0[8], kf1[8], kf2[8], kf3[8], jf0[8], jf1[8], jf2[8], jf3[8];
        up8(kr0, kf0); up8(kr1, kf1); up8(kr2, kf2); up8(kr3, kf3);
        up8(jr0, jf0); up8(jr1, jf1); up8(jr2, jf2); up8(jr3, jf3);
#pragma unroll
        for (int e = 0; e < 8; ++e) {
          a44[0]  += kf0[e] * jf0[e]; a44[1]  += kf0[e] * jf1[e];
          a44[2]  += kf0[e] * jf2[e]; a44[3]  += kf0[e] * jf3[e];
          a44[4]  += kf1[e] * jf0[e]; a44[5]  += kf1[e] * jf1[e];
          a44[6]  += kf1[e] * jf2[e]; a44[7]  += kf1[e] * jf3[e];
          a44[8]  += kf2[e] * jf0[e]; a44[9]  += kf2[e] * jf1[e];
          a44[10] += kf2[e] * jf2[e]; a44[11] += kf2[e] * jf3[e];
          a44[12] += kf3[e] * jf0[e]; a44[13] += kf3[e] * jf1[e];
          a44[14] += kf3[e] * jf2[e]; a44[15] += kf3[e] * jf3[e];
        }
      }
    }
#pragma unroll
    for (int r = 0; r < 4; ++r)
#pragma unroll
      for (int s = 0; s < 4; ++s) {
        int t = tb + r, j = jb + s;
        float val = 0.f;
        if (j < t) val = __expf((GclL[t] - glL[t]) - GclL[j]) * blL[j] * a44[r * 4 + s];
        AmL[t * 68 + j] = val;
      }
  }
  __syncthreads();

  // forward substitution (rank-4 blocked); thread = one column of [V | Dp*K]
  if (tid < 288) {
    int j = tid;
    float m[64];
    if (j < 192) {
      const u16* up = Uv + (size_t)bT0 * VALD + h * DV_ + j;
#pragma unroll
      for (int t = 0; t < 64; ++t) m[t] = bf2f(up[(size_t)t * VALD]);
    } else {
      int d = j - 192;
#pragma unroll
      for (int t = 0; t < 64; ++t) m[t] = DplL[t] * bf2f(ktL[t * 104 + d]);
    }
#pragma unroll
    for (int t0 = 0; t0 < 64; t0 += 4) {
      {
        f32x4 a1 = *(const f32x4*)&AmL[(t0 + 1) * 68 + t0];
        m[t0 + 1] -= a1[0] * m[t0];
        f32x4 a2 = *(const f32x4*)&AmL[(t0 + 2) * 68 + t0];
        m[t0 + 2] -= a2[0] * m[t0] + a2[1] * m[t0 + 1];
        f32x4 a3 = *(const f32x4*)&AmL[(t0 + 3) * 68 + t0];
        m[t0 + 3] -= a3[0] * m[t0] + a3[1] * m[t0 + 1] + a3[2] * m[t0 + 2];
      }
#pragma unroll
      for (int tp = t0 + 4; tp < 64; ++tp) {
        f32x4 a = *(const f32x4*)&AmL[tp * 68 + t0];
        m[tp] -= a[0] * m[t0] + a[1] * m[t0 + 1] + a[2] * m[t0 + 2] + a[3] * m[t0 + 3];
      }
    }
    if (j < 192) {
      u16* up = Uv + (size_t)bT0 * VALD + h * DV_ + j;
#pragma unroll
      for (int t = 0; t < 64; ++t) up[(size_t)t * VALD] = f2bf(m[t]);
    } else {
      int d = j - 192;
      u16* wp = Wg + (size_t)bT0 * KEYD + h * DK_ + d;
#pragma unroll
      for (int t = 0; t < 64; ++t) wp[(size_t)t * KEYD] = f2bf(m[t]);
    }
  }
}

// serial: per (bh, jq of DV/8): S_{c+1} = lam*S + K'^T E, E = U - W S (E written in place
// over U, bf16); snapshot chunk-start S into Schk.
__global__ __launch_bounds__(256) void serial_state(
    const u16* __restrict__ kc, const u16* __restrict__ Wg, u16* __restrict__ Ue,
    const float* __restrict__ cdArr, const float* __restrict__ lamArr,
    u16* __restrict__ Schk) {
  __shared__ u16 WtL[64 * 104];
  __shared__ u16 ktL[64 * 104];
  __shared__ float Sl[96 * 24];
  __shared__ float ElL[64 * 24];
  __shared__ float cdl[64];
  __shared__ float lamS;
  int tid = threadIdx.x;
  int jq = blockIdx.x & 7, bh = blockIdx.x >> 3, h = bh & 15, b = bh >> 4;
  for (int i = tid; i < 96 * 24; i += 256) Sl[i] = 0.f;

  for (int c = 0; c < NC_; ++c) {
    int flat = bh * NC_ + c;
    int bT0 = b * T_ + c * 64;
    __syncthreads();
    // stage W, k tiles; cd, lam; snapshot S (chunk-start state)
    {
      const u32* wg = (const u32*)(Wg + (size_t)bT0 * KEYD + h * DK_);
      const u32* kg = (const u32*)(kc + (size_t)bT0 * KEYD + h * DK_);
      for (int i = tid; i < 3072; i += 256) {
        int t = i / 48, dd = i - t * 48;
        ((u32*)WtL)[t * 52 + dd] = wg[(size_t)t * (KEYD / 2) + dd];
        ((u32*)ktL)[t * 52 + dd] = kg[(size_t)t * (KEYD / 2) + dd];
      }
      if (tid < 64) cdl[tid] = cdArr[(size_t)flat * 64 + tid];
      if (tid == 0) lamS = lamArr[flat];
      for (int i = tid; i < 2304; i += 256) {
        int d = i / 24, jl = i - d * 24;
        Schk[((size_t)flat * DK_ + d) * DV_ + jq * 24 + jl] = f2bf(Sl[i]);
      }
    }
    __syncthreads();
    // E = U - W S ; write global bf16 (unscaled), LDS f32 (scaled by cd)
    {
      int t = tid >> 2, jg = tid & 3;
      size_t gbase = (size_t)(bT0 + t) * VALD + h * DV_ + jq * 24 + jg * 6;
      const u32* up32 = (const u32*)(Ue + gbase);
      u32 u0 = up32[0], u1 = up32[1], u2 = up32[2];
      float ac[6] = {bflo(u0), bfhi(u0), bflo(u1), bfhi(u1), bflo(u2), bfhi(u2)};
#pragma unroll
      for (int dd8 = 0; dd8 < 12; ++dd8) {
        uint4 wv = *(const uint4*)((const char*)WtL + t * 208 + dd8 * 16);
        float wf[8]; up8(wv, wf);
#pragma unroll
        for (int e = 0; e < 8; ++e) {
          int d = dd8 * 8 + e;
          const float2* sp = (const float2*)&Sl[d * 24 + jg * 6];
          float2 s0 = sp[0], s1 = sp[1], s2 = sp[2];
          ac[0] -= wf[e] * s0.x; ac[1] -= wf[e] * s0.y; ac[2] -= wf[e] * s1.x;
          ac[3] -= wf[e] * s1.y; ac[4] -= wf[e] * s2.x; ac[5] -= wf[e] * s2.y;
        }
      }
      u32* ow = (u32*)(Ue + gbase);
      ow[0] = ((u32)f2bf(ac[1]) << 16) | f2bf(ac[0]);
      ow[1] = ((u32)f2bf(ac[3]) << 16) | f2bf(ac[2]);
      ow[2] = ((u32)f2bf(ac[5]) << 16) | f2bf(ac[4]);
      float cdv = cdl[t];
      float2* el = (float2*)&ElL[t * 24 + jg * 6];
      el[0] = make_float2(cdv * ac[0], cdv * ac[1]);
      el[1] = make_float2(cdv * ac[2], cdv * ac[3]);
      el[2] = make_float2(cdv * ac[4], cdv * ac[5]);
    }
    __syncthreads();
    // S = lam*S + K'^T E  (384 units of (d, 6 cols))
    float lamv = lamS;
#pragma unroll
    for (int r = 0; r < 2; ++r) {
      int unit = tid + 256 * r;
      if (unit < 384) {
        int d = unit >> 2, jg = unit & 3;
        float2* sp = (float2*)&Sl[d * 24 + jg * 6];
        float2 s0 = sp[0], s1 = sp[1], s2 = sp[2];
        float ac[6] = {lamv * s0.x, lamv * s0.y, lamv * s1.x,
                       lamv * s1.y, lamv * s2.x, lamv * s2.y};
#pragma unroll
        for (int t = 0; t < 64; ++t) {
          float kv = bf2f(ktL[t * 104 + d]);
          const float2* ep = (const float2*)&ElL[t * 24 + jg * 6];
          float2 e0 = ep[0], e1 = ep[1], e2 = ep[2];
          ac[0] += kv * e0.x; ac[1] += kv * e0.y; ac[2] += kv * e1.x;
          ac[3] += kv * e1.y; ac[4] += kv * e2.x; ac[5] += kv * e2.y;
        }
        sp[0] = make_float2(ac[0], ac[1]);
        sp[1] = make_float2(ac[2], ac[3]);
        sp[2] = make_float2(ac[4], ac[5]);
      }
    }
  }
}

// pass3: per (bh,chunk): O = diag(D) (Q S0) + tril_incl(Bm) E, Bm[t,t'] = exp(Gc_t-Gc_t') beta_t' (q_t.k_t')
__global__ __launch_bounds__(256) void chunk_out(
    const u16* __restrict__ qc, const u16* __restrict__ kc, const u16* __restrict__ Ee,
    const u16* __restrict__ Schk, const float* __restrict__ Gcum,
    const float* __restrict__ beta, u16* __restrict__ osc) {
  __shared__ char pool[61440];
  u16* qL = (u16*)pool;                      // 64x104 u16 = 13312
  float* BmL = (float*)(pool + 13312);       // 64x65  f32 = 16640 -> 29952
  u16* kL = (u16*)(pool + 29952);            // 13312 (phase A)
  u16* ShL = (u16*)(pool + 29952);           // 96x96 u16 = 18432 (phase B)
  u16* EhL = (u16*)(pool + 48384);           // 64x96 u16 = 12288 (phase B)
  float* GclL = (float*)(pool + 60672);      // 64
  float* blL = GclL + 64;
  float* DlL = blL + 64;

  int tid = threadIdx.x;
  int flat = blockIdx.x;
  int c = flat & 31, bh = flat >> 5, h = bh & 15, b = bh >> 4;
  int bT0 = b * T_ + c * 64;

  {
    const u32* qg = (const u32*)(qc + (size_t)bT0 * KEYD + h * DK_);
    const u32* kg = (const u32*)(kc + (size_t)bT0 * KEYD + h * DK_);
    for (int i = tid; i < 3072; i += 256) {
      int t = i / 48, dd = i - t * 48;
      ((u32*)qL)[t * 52 + dd] = qg[(size_t)t * (KEYD / 2) + dd];
      ((u32*)kL)[t * 52 + dd] = kg[(size_t)t * (KEYD / 2) + dd];
    }
    if (tid < 64) {
      float gv = Gcum[(size_t)flat * 64 + tid];
      GclL[tid] = gv;
      DlL[tid] = __expf(gv);
      blL[tid] = beta[(size_t)(bT0 + tid) * H_ + h];
    }
  }
  __syncthreads();
  // Bm (rows t from q, cols t' from k), incl diagonal
  {
    int tb = (tid >> 4) << 2, jb = (tid & 15) << 2;
    float a44[16];
#pragma unroll
    for (int i = 0; i < 16; ++i) a44[i] = 0.f;
    if (jb <= tb) {
#pragma unroll
      for (int dd8 = 0; dd8 < 12; ++dd8) {
        uint4 kr0 = *(const uint4*)((const char*)qL + (tb + 0) * 208 + dd8 * 16);
        uint4 kr1 = *(const uint4*)((const char*)qL + (tb + 1) * 208 + dd8 * 16);
        uint4 kr2 = *(const uint4*)((const char*)qL + (tb + 2) * 208 + dd8 * 16);
        uint4 kr3 = *(const uint4*)((const char*)qL + (tb + 3) * 208 + dd8 * 16);
        uint4 jr0 = *(const uint4*)((const char*)kL + (jb + 0) * 208 + dd8 * 16);
        uint4 jr1 = *(const uint4*)((const char*)kL + (jb + 1) * 208 + dd8 * 16);
        uint4 jr2 = *(const uint4*)((const char*)kL + (jb + 2) * 208 + dd8 * 16);
        uint4 jr3 = *(const uint4*)((const char*)kL + (jb + 3) * 208 + dd8 * 16);
        float kf0[8], kf1[8], kf2[8], kf3[8], jf0[8], jf1[8], jf2[8], jf3[8];
        up8(kr0, kf0); up8(kr1, kf1); up8(kr2, kf2); up8(kr3, kf3);
        up8(jr0, jf0); up8(jr1, jf1); up8(jr2, jf2); up8(jr3, jf3);
#pragma unroll
        for (int e = 0; e < 8; ++e) {
          a44[0]  += kf0[e] * jf0[e]; a44[1]  += kf0[e] * jf1[e];
          a44[2]  += kf0[e] * jf2[e]; a44[3]  += kf0[e] * jf3[e];
          a44[4]  += kf1[e] * jf0[e]; a44[5]  += kf1[e] * jf1[e];
          a44[6]  += kf1[e] * jf2[e]; a44[7]  += kf1[e] * jf3[e];
          a44[8]  += kf2[e] * jf0[e]; a44[9]  += kf2[e] * jf1[e];
          a44[10] += kf2[e] * jf2[e]; a44[11] += kf2[e] * jf3[e];
          a44[12] += kf3[e] * jf0[e]; a44[13] += kf3[e] * jf1[e];
          a44[14] += kf3[e] * jf2[e]; a44[15] += kf3[e] * jf3[e];
        }
      }
    }
#pragma unroll
    for (int r = 0; r < 4; ++r)
#pragma unroll
      for (int s = 0; s < 4; ++s) {
        int t = tb + r, j = jb + s;
        float val = 0.f;
        if (j <= t) val = __expf(GclL[t] - GclL[j]) * blL[j] * a44[r * 4 + s];
        BmL[t * 65 + j] = val;
      }
  }
  __syncthreads();

#pragma unroll
  for (int half = 0; half < 2; ++half) {
    // stage S0 (96x96) and E (64x96) halves
    {
      const u32* sg = (const u32*)(Schk + ((size_t)flat * DK_) * DV_ + half * 96);
      for (int i = tid; i < 4608; i += 256) {
        int d = i / 48, dd = i - d * 48;
        ((u32*)ShL)[d * 48 + dd] = sg[(size_t)d * (DV_ / 2) + dd];
      }
      const u32* eg = (const u32*)(Ee + (size_t)bT0 * VALD + h * DV_ + half * 96);
      for (int i = tid; i < 3072; i += 256) {
        int t = i / 48, dd = i - t * 48;
        ((u32*)EhL)[t * 48 + dd] = eg[(size_t)t * (VALD / 2) + dd];
      }
    }
    __syncthreads();
    {
      int t = tid >> 2, jg = tid & 3;
      float acc[24];
#pragma unroll
      for (int i = 0; i < 24; ++i) acc[i] = 0.f;
#pragma unroll
      for (int dd8 = 0; dd8 < 12; ++dd8) {
        uint4 qv = *(const uint4*)((const char*)qL + t * 208 + dd8 * 16);
        float qf[8]; up8(qv, qf);
#pragma unroll
        for (int e = 0; e < 8; ++e) {
          int d = dd8 * 8 + e;
          const uint4* sp = (const uint4*)((const char*)ShL + d * 192 + jg * 48);
          float sf[24];
          up8(sp[0], sf); up8(sp[1], sf + 8); up8(sp[2], sf + 16);
#pragma unroll
          for (int i = 0; i < 24; ++i) acc[i] += qf[e] * sf[i];
        }
      }
      float dt = DlL[t];
#pragma unroll
      for (int i = 0; i < 24; ++i) acc[i] *= dt;
      int tpmax = ((tid >> 6) << 4) + 16;   // wave-uniform bound (t < tpmax within wave)
      for (int tp = 0; tp < tpmax; ++tp) {
        float bmv = BmL[t * 65 + tp];
        const uint4* ep = (const uint4*)((const char*)EhL + tp * 192 + jg * 48);
        float ef[24];
        up8(ep[0], ef); up8(ep[1], ef + 8); up8(ep[2], ef + 16);
#pragma unroll
        for (int i = 0; i < 24; ++i) acc[i] += bmv * ef[i];
      }
      u32* ow = (u32*)(osc + (size_t)(bT0 + t) * VALD + h * DV_ + half * 96 + jg * 24);
#pragma unroll
      for (int i = 0; i < 12; ++i)
        ow[i] = ((u32)f2bf(acc[2 * i + 1]) << 16) | f2bf(acc[2 * i]);
    }
    __syncthreads();
  }
}

// ---------- gated RMSNorm -> bf16 ----------
__global__ __launch_bounds__(256) void rmsnorm_gate(const u16* __restrict__ o,
    const u16* __restrict__ Pg, const float* __restrict__ w, u16* __restrict__ onb) {
  int bt = blockIdx.x;
  int tid = threadIdx.x, h = tid >> 4, li = tid & 15;
  const u16* orow = o + (size_t)bt * VALD + h * DV_;
  const u16* grow = Pg + (size_t)bt * VALD + h * DV_;
  float y[12]; float ss = 0.f;
#pragma unroll
  for (int jj = 0; jj < 12; ++jj) {
    float v = bf2f(orow[li + jj * 16]);
    y[jj] = v; ss += v * v;
  }
  ss += __shfl_xor(ss, 1); ss += __shfl_xor(ss, 2);
  ss += __shfl_xor(ss, 4); ss += __shfl_xor(ss, 8);
  float rms = rsqrtf(ss * (1.f / DV_) + 1e-6f);
  u16* out = onb + (size_t)bt * VALD + h * DV_;
#pragma unroll
  for (int jj = 0; jj < 12; ++jj) {
    int c = li + jj * 16;
    float gv = bf2f(grow[c]);
    float sig = 1.f / (1.f + __expf(-gv));
    out[c] = f2bf(y[jj] * rms * w[c] * sig);
  }
}

// ---------- launch ----------
extern "C" void kernel_launch(void* const* d_in, const int* in_sizes, int n_in,
                              void* d_out, int out_size, void* d_ws, size_t ws_size,
                              hipStream_t stream) {
  (void)in_sizes; (void)n_in; (void)out_size; (void)ws_size;
  const float* x      = (const float*)d_in[0];
  const float* Wq     = (const float*)d_in[1];
  const float* Wk     = (const float*)d_in[2];
  const float* Wv     = (const float*)d_in[3];
  const float* Wb     = (const float*)d_in[4];
  const float* Wa     = (const float*)d_in[5];
  const float* Wg     = (const float*)d_in[6];
  const float* Wo     = (const float*)d_in[7];
  const float* cqw    = (const float*)d_in[8];
  const float* ckw    = (const float*)d_in[9];
  const float* cvw    = (const float*)d_in[10];
  const float* A_log  = (const float*)d_in[11];
  const float* dt_bias= (const float*)d_in[12];
  const float* onw    = (const float*)d_in[13];
  float* out = (float*)d_out;

  char* ws = (char*)d_ws;
  u16*   xb    = (u16*)  (ws + 0);            // 16,777,216
  u16*   WT    = (u16*)  (ws + 16777216);     // 37,748,736
  u16*   qc    = (u16*)  (ws + 0);            // 12,582,912 (alias after gemm1)
  u16*   kc    = (u16*)  (ws + 12582912);     // 12,582,912
  u16*   vc    = (u16*)  (ws + 25165824);     // 25,165,824 (also U -> E, in place)
  u16*   Pqkv  = (u16*)  (ws + 54525952);     // 50,331,648
  u16*   Wbuf  = (u16*)  (ws + 54525952);     // 12,582,912 (alias after convs)
  u16*   Schk  = (u16*)  (ws + 67108864);     // 37,748,736
  u16*   Pg    = (u16*)  (ws + 104857600);    // 25,165,824
  u16*   osc   = (u16*)  (ws + 130023424);    // 25,165,824
  float* beta  = (float*)(ws + 155189248);    // 262,144
  float* gg    = (float*)(ws + 155451392);    // 262,144
  float* Gcum  = (float*)(ws + 155713536);    // 262,144
  float* cdArr = (float*)(ws + 155975680);    // 262,144
  float* lamArr= (float*)(ws + 156237824);    // 4,096  -> total 156,241,920
  u16*   onb   = (u16*)  (ws + 54525952);     // alias (after pass3)
  u16*   WoT   = (u16*)  (ws + 79691776);     // alias (after pass3)

  int n4 = B_ * T_ * D_ / 4;
  cast_x<<<(n4 + 255) / 256, 256, 0, stream>>>(x, xb, n4);
  transpose_cast<<<dim3(48, 64), 256, 0, stream>>>(Wq, WT, 2048, 1536);
  transpose_cast<<<dim3(48, 64), 256, 0, stream>>>(Wk, WT + (size_t)1536 * 2048, 2048, 1536);
  transpose_cast<<<dim3(96, 64), 256, 0, stream>>>(Wv, WT + (size_t)3072 * 2048, 2048, 3072);
  transpose_cast<<<dim3(96, 64), 256, 0, stream>>>(Wg, WT + (size_t)6144 * 2048, 2048, 3072);

  gemm_bt<1><<<dim3(NPROJ / 128, (B_ * T_) / 128), 256, 0, stream>>>(
      xb, WT, Pqkv, Pg, nullptr, B_ * T_, NPROJ, D_, PQK, PQK, VALD);
  proj_bg<<<(B_ * T_) / 4, 256, 0, stream>>>(x, Wb, Wa, A_log, dt_bias, beta, gg);
  conv_qk<<<B_ * T_, 256, 0, stream>>>(Pqkv, cqw, ckw, qc, kc);
  conv_v<<<(B_ * T_ * VALD) / 256, 256, 0, stream>>>(Pqkv, cvw, vc);

  chunk_prep<<<B_ * H_ * NC_, 320, 0, stream>>>(kc, vc, gg, beta, Wbuf, Gcum, cdArr, lamArr);
  serial_state<<<B_ * H_ * 8, 256, 0, stream>>>(kc, Wbuf, vc, cdArr, lamArr, Schk);
  chunk_out<<<B_ * H_ * NC_, 256, 0, stream>>>(qc, kc, vc, Schk, Gcum, beta, osc);

  rmsnorm_gate<<<B_ * T_, 256, 0, stream>>>(osc, Pg, onw, onb);
  transpose_cast<<<dim3(64, 96), 256, 0, stream>>>(Wo, WoT, 3072, 2048);
  gemm_bt<0><<<dim3(D_ / 128, (B_ * T_) / 128), 256, 0, stream>>>(
      onb, WoT, nullptr, nullptr, out, B_ * T_, D_, VALD, 0, 0, 0);
}

// Round 4
// 989.020 us; speedup vs baseline: 1.7766x; 1.4232x over previous
//
#include <hip/hip_runtime.h>

#define B_ 2
#define T_ 2048
#define D_ 2048
#define H_ 16
#define DK_ 96
#define DV_ 192
#define KEYD 1536
#define VALD 3072
#define NPROJ 9216
#define PQK 6144     // Pqkv row width (q|k|v)
#define KS_ 4
#define C_ 64
#define NC_ 32       // T_/C_

typedef unsigned short u16;
typedef unsigned int u32;
typedef __bf16 bf16x8 __attribute__((ext_vector_type(8)));
typedef float f32x4 __attribute__((ext_vector_type(4)));

// ---------- helpers ----------
__device__ __forceinline__ u16 f2bf(float f) {
  unsigned u = __float_as_uint(f);
  u += 0x7FFF + ((u >> 16) & 1);
  return (u16)(u >> 16);
}
__device__ __forceinline__ float bf2f(u16 v) { return __uint_as_float((unsigned)v << 16); }
__device__ __forceinline__ float bflo(u32 w) { return __uint_as_float(w << 16); }
__device__ __forceinline__ float bfhi(u32 w) { return __uint_as_float(w & 0xFFFF0000u); }
__device__ __forceinline__ void up8(uint4 u, float* f) {
  f[0]=bflo(u.x); f[1]=bfhi(u.x); f[2]=bflo(u.y); f[3]=bfhi(u.y);
  f[4]=bflo(u.z); f[5]=bfhi(u.z); f[6]=bflo(u.w); f[7]=bfhi(u.w);
}

__device__ __forceinline__ void gll16(const void* g, void* lds) {
  __builtin_amdgcn_global_load_lds(
      (const __attribute__((address_space(1))) void*)g,
      (__attribute__((address_space(3))) void*)lds, 16, 0, 0);
}

// ---------- casts / transposes ----------
__global__ __launch_bounds__(256) void cast_x(const float* __restrict__ in,
                                              u16* __restrict__ out, int n4) {
  int i = blockIdx.x * 256 + threadIdx.x;
  if (i < n4) {
    float4 v = reinterpret_cast<const float4*>(in)[i];
    ushort4 o;
    o.x = f2bf(v.x); o.y = f2bf(v.y); o.z = f2bf(v.z); o.w = f2bf(v.w);
    reinterpret_cast<ushort4*>(out)[i] = o;
  }
}

__global__ __launch_bounds__(256) void transpose_cast(const float* __restrict__ src,
                                                      u16* __restrict__ dst, int R, int C) {
  __shared__ float tile[32][33];
  int tx = threadIdx.x & 31, ty = threadIdx.x >> 5;
  int c0 = blockIdx.x * 32, r0 = blockIdx.y * 32;
#pragma unroll
  for (int j = 0; j < 4; ++j)
    tile[ty + j * 8][tx] = src[(size_t)(r0 + ty + j * 8) * C + c0 + tx];
  __syncthreads();
#pragma unroll
  for (int j = 0; j < 4; ++j)
    dst[(size_t)(c0 + ty + j * 8) * R + r0 + tx] = f2bf(tile[tx][ty + j * 8]);
}

// ---------- bf16 MFMA GEMM: C = A[M,K] * BT[N,K]^T ----------
template <int OUT16>
__global__ __launch_bounds__(256) void gemm_bt(const u16* __restrict__ A,
                                               const u16* __restrict__ BT,
                                               u16* __restrict__ C0, u16* __restrict__ C1,
                                               float* __restrict__ Cf,
                                               int M, int N, int K, int nsplit, int s0, int s1) {
  __shared__ u16 As[128 * 32];
  __shared__ u16 Bs[128 * 32];
  int tid = threadIdx.x;
  int wave = tid >> 6, lane = tid & 63;
  int l15 = lane & 15, l16 = lane >> 4;
  int m0 = blockIdx.y * 128, n0 = blockIdx.x * 128;
  int wm = (wave >> 1) * 64, wn = (wave & 1) * 64;
  f32x4 acc[4][4] = {};
  int nkt = K >> 5;
  for (int kt = 0; kt < nkt; ++kt) {
    int k0 = kt << 5;
    __syncthreads();
#pragma unroll
    for (int rr = 0; rr < 2; ++rr) {
      int idx = tid + rr * 256;
      int row = idx >> 2, kc8 = (idx & 3) * 8;
      unsigned loff = (unsigned)(rr * 256 + wave * 64) * 16;
      gll16(A + (size_t)(m0 + row) * K + k0 + kc8, (char*)As + loff);
      gll16(BT + (size_t)(n0 + row) * K + k0 + kc8, (char*)Bs + loff);
    }
    __syncthreads();
    bf16x8 af[4], bfr[4];
#pragma unroll
    for (int i = 0; i < 4; ++i)
      af[i] = *reinterpret_cast<const bf16x8*>(&As[(wm + i * 16 + l15) * 32 + l16 * 8]);
#pragma unroll
    for (int i = 0; i < 4; ++i)
      bfr[i] = *reinterpret_cast<const bf16x8*>(&Bs[(wn + i * 16 + l15) * 32 + l16 * 8]);
#pragma unroll
    for (int mi = 0; mi < 4; ++mi)
#pragma unroll
      for (int ni = 0; ni < 4; ++ni)
        acc[mi][ni] = __builtin_amdgcn_mfma_f32_16x16x32_bf16(af[mi], bfr[ni], acc[mi][ni], 0, 0, 0);
  }
#pragma unroll
  for (int mi = 0; mi < 4; ++mi)
#pragma unroll
    for (int ni = 0; ni < 4; ++ni)
#pragma unroll
      for (int j = 0; j < 4; ++j) {
        int row = m0 + wm + mi * 16 + l16 * 4 + j;
        int col = n0 + wn + ni * 16 + l15;
        if (OUT16) {
          if (col < nsplit) C0[(size_t)row * s0 + col] = f2bf(acc[mi][ni][j]);
          else              C1[(size_t)row * s1 + col - nsplit] = f2bf(acc[mi][ni][j]);
        } else {
          Cf[(size_t)row * N + col] = acc[mi][ni][j];
        }
      }
}

// ---------- beta / g projections ----------
__global__ __launch_bounds__(256) void proj_bg(const float* __restrict__ x,
    const float* __restrict__ Wb, const float* __restrict__ Wa,
    const float* __restrict__ A_log, const float* __restrict__ dt_bias,
    float* __restrict__ beta, float* __restrict__ gg) {
  __shared__ float xs[4 * 2048];
  __shared__ float red[4][32][8];
  int tid = threadIdx.x;
  int r0 = blockIdx.x * 4;
  for (int i = tid; i < 4 * 2048; i += 256)
    xs[i] = x[(size_t)r0 * D_ + i];
  __syncthreads();
  int colg = tid & 31, ks = tid >> 5;
  const float* W = (colg < 16) ? Wb : Wa;
  int wc = colg & 15;
  float p0 = 0, p1 = 0, p2 = 0, p3 = 0;
  int kbeg = ks * 256;
  for (int k = kbeg; k < kbeg + 256; ++k) {
    float wv = W[k * H_ + wc];
    p0 += xs[k] * wv;
    p1 += xs[2048 + k] * wv;
    p2 += xs[4096 + k] * wv;
    p3 += xs[6144 + k] * wv;
  }
  red[0][colg][ks] = p0; red[1][colg][ks] = p1;
  red[2][colg][ks] = p2; red[3][colg][ks] = p3;
  __syncthreads();
  if (tid < 128) {
    int row = tid >> 5, col = tid & 31;
    float d = 0;
#pragma unroll
    for (int i = 0; i < 8; ++i) d += red[row][col][i];
    int r = r0 + row;
    if (col < 16) {
      beta[(size_t)r * H_ + col] = 1.f / (1.f + __expf(-d));
    } else {
      int hh = col - 16;
      float z = d + dt_bias[hh];
      float sp = (z > 20.f) ? z : log1pf(__expf(z));
      gg[(size_t)r * H_ + hh] = -__expf(A_log[hh]) * sp;
    }
  }
}

// ---------- conv(KS=4)+SiLU+L2norm for q,k ----------
__global__ __launch_bounds__(256) void conv_qk(const u16* __restrict__ Pqkv,
    const float* __restrict__ wq, const float* __restrict__ wk,
    u16* __restrict__ qc, u16* __restrict__ kc) {
  int bt = blockIdx.x;
  int t = bt & (T_ - 1);
  int tid = threadIdx.x, h = tid >> 4, li = tid & 15;
#pragma unroll
  for (int part = 0; part < 2; ++part) {
    const float* w = part ? wk : wq;
    const u16* base = Pqkv + (size_t)bt * PQK + part * KEYD + h * DK_;
    float y[6]; float ss = 0.f;
#pragma unroll
    for (int jj = 0; jj < 6; ++jj) {
      int c = li + jj * 16;
      int ch = h * DK_ + c;
      float a = 0.f;
#pragma unroll
      for (int j = 0; j < KS_; ++j) {
        int dt = j - (KS_ - 1);
        if (t + dt >= 0) a += bf2f(base[(ptrdiff_t)dt * PQK + c]) * w[ch * KS_ + j];
      }
      float yv = a / (1.f + __expf(-a));
      y[jj] = yv; ss += yv * yv;
    }
    ss += __shfl_xor(ss, 1); ss += __shfl_xor(ss, 2);
    ss += __shfl_xor(ss, 4); ss += __shfl_xor(ss, 8);
    float rn = rsqrtf(ss + 1e-12f);
    u16* out = (part ? kc : qc) + (size_t)bt * KEYD + h * DK_;
#pragma unroll
    for (int jj = 0; jj < 6; ++jj) out[li + jj * 16] = f2bf(y[jj] * rn);
  }
}

// ---------- conv(KS=4)+SiLU for v ----------
__global__ __launch_bounds__(256) void conv_v(const u16* __restrict__ Pqkv,
    const float* __restrict__ wv, u16* __restrict__ vc) {
  int id = blockIdx.x * 256 + threadIdx.x;
  int bt = id / VALD, c = id - bt * VALD;
  int t = bt & (T_ - 1);
  const u16* base = Pqkv + (size_t)bt * PQK + 2 * KEYD + c;
  float a = 0.f;
#pragma unroll
  for (int j = 0; j < KS_; ++j) {
    int dt = j - (KS_ - 1);
    if (t + dt >= 0) a += bf2f(base[(ptrdiff_t)dt * PQK]) * wv[c * KS_ + j];
  }
  vc[id] = f2bf(a / (1.f + __expf(-a)));
}

// ================= chunked gated-delta scan =================
__global__ __launch_bounds__(320) void chunk_prep(
    const u16* __restrict__ kc, u16* __restrict__ Uv /* = vc, in-place */,
    const float* __restrict__ gg, const float* __restrict__ beta,
    u16* __restrict__ Wg, float* __restrict__ Gcum,
    float* __restrict__ cdArr, float* __restrict__ lamArr) {
  __shared__ u16 ktL[64 * 104];      // padded rows
  __shared__ float AmL[64 * 68];     // padded rows
  __shared__ float glL[64], GclL[64], blL[64], DplL[64];
  int tid = threadIdx.x;
  int flat = blockIdx.x;
  int c = flat & 31, bh = flat >> 5, h = bh & 15, b = bh >> 4;
  int bT0 = b * T_ + c * 64;

  {
    const u32* kg = (const u32*)(kc + (size_t)bT0 * KEYD + h * DK_);
    for (int i = tid; i < 3072; i += 320) {
      int t = i / 48, dd = i - t * 48;
      ((u32*)ktL)[t * 52 + dd] = kg[(size_t)t * (KEYD / 2) + dd];
    }
  }
  if (tid < 64) {
    float g = gg[(size_t)(bT0 + tid) * H_ + h];
    float bv = beta[(size_t)(bT0 + tid) * H_ + h];
    float v = g;
#pragma unroll
    for (int off = 1; off < 64; off <<= 1) {
      float u = __shfl_up(v, off);
      if (tid >= off) v += u;
    }
    float g63 = __shfl(v, 63);
    glL[tid] = g; GclL[tid] = v; blL[tid] = bv; DplL[tid] = __expf(v - g);
    Gcum[(size_t)flat * 64 + tid] = v;
    cdArr[(size_t)flat * 64 + tid] = bv * __expf(g63 - v);
    if (tid == 63) lamArr[flat] = __expf(v);
  }
  __syncthreads();

  if (tid < 256) {
    int tb = (tid >> 4) << 2, jb = (tid & 15) << 2;
    float a44[16];
#pragma unroll
    for (int i = 0; i < 16; ++i) a44[i] = 0.f;
    if (jb <= tb) {
#pragma unroll
      for (int dd8 = 0; dd8 < 12; ++dd8) {
        uint4 kr0 = *(const uint4*)((const char*)ktL + (tb + 0) * 208 + dd8 * 16);
        uint4 kr1 = *(const uint4*)((const char*)ktL + (tb + 1) * 208 + dd8 * 16);
        uint4 kr2 = *(const uint4*)((const char*)ktL + (tb + 2) * 208 + dd8 * 16);
        uint4 kr3 = *(const uint4*)((const char*)ktL + (tb + 3) * 208 + dd8 * 16);
        uint4 jr0 = *(const uint4*)((const char*)ktL + (jb + 0) * 208 + dd8 * 16);
        uint4 jr1 = *(const uint4*)((const char*)ktL + (jb + 1) * 208 + dd8 * 16);
        uint4 jr2 = *(const uint4*)((const char*)ktL + (jb + 2) * 208 + dd8 * 16);
        uint4 jr3 = *(const uint4*)((const char*)ktL + (jb + 3) * 208 + dd8 * 16);
        float kf0[8], kf1[8], kf2[8], kf3[8], jf0[8], jf1[8], jf2[8], jf3[8];
        up8(kr0, kf0); up8(kr1, kf1); up8(kr2, kf2); up8(kr3, kf3);
        up8(jr0, jf0); up8(jr1, jf1); up8(jr2, jf2); up8(jr3, jf3);
#pragma unroll
        for (int e = 0; e < 8; ++e) {
          a44[0]  += kf0[e] * jf0[e]; a44[1]  += kf0[e] * jf1[e];
          a44[2]  += kf0[e] * jf2[e]; a44[3]  += kf0[e] * jf3[e];
          a44[4]  += kf1[e] * jf0[e]; a44[5]  += kf1[e] * jf1[e];
          a44[6]  += kf1[e] * jf2[e]; a44[7]  += kf1[e] * jf3[e];
          a44[8]  += kf2[e] * jf0[e]; a44[9]  += kf2[e] * jf1[e];
          a44[10] += kf2[e] * jf2[e]; a44[11] += kf2[e] * jf3[e];
          a44[12] += kf3[e] * jf0[e]; a44[13] += kf3[e] * jf1[e];
          a44[14] += kf3[e] * jf2[e]; a44[15] += kf3[e] * jf3[e];
        }
      }
    }
#pragma unroll
    for (int r = 0; r < 4; ++r)
#pragma unroll
      for (int s = 0; s < 4; ++s) {
        int t = tb + r, j = jb + s;
        float val = 0.f;
        if (j < t) val = __expf((GclL[t] - glL[t]) - GclL[j]) * blL[j] * a44[r * 4 + s];
        AmL[t * 68 + j] = val;
      }
  }
  __syncthreads();

  if (tid < 288) {
    int j = tid;
    float m[64];
    if (j < 192) {
      const u16* up = Uv + (size_t)bT0 * VALD + h * DV_ + j;
#pragma unroll
      for (int t = 0; t < 64; ++t) m[t] = bf2f(up[(size_t)t * VALD]);
    } else {
      int d = j - 192;
#pragma unroll
      for (int t = 0; t < 64; ++t) m[t] = DplL[t] * bf2f(ktL[t * 104 + d]);
    }
#pragma unroll
    for (int t0 = 0; t0 < 64; t0 += 4) {
      {
        f32x4 a1 = *(const f32x4*)&AmL[(t0 + 1) * 68 + t0];
        m[t0 + 1] -= a1[0] * m[t0];
        f32x4 a2 = *(const f32x4*)&AmL[(t0 + 2) * 68 + t0];
        m[t0 + 2] -= a2[0] * m[t0] + a2[1] * m[t0 + 1];
        f32x4 a3 = *(const f32x4*)&AmL[(t0 + 3) * 68 + t0];
        m[t0 + 3] -= a3[0] * m[t0] + a3[1] * m[t0 + 1] + a3[2] * m[t0 + 2];
      }
#pragma unroll
      for (int tp = t0 + 4; tp < 64; ++tp) {
        f32x4 a = *(const f32x4*)&AmL[tp * 68 + t0];
        m[tp] -= a[0] * m[t0] + a[1] * m[t0 + 1] + a[2] * m[t0 + 2] + a[3] * m[t0 + 3];
      }
    }
    if (j < 192) {
      u16* up = Uv + (size_t)bT0 * VALD + h * DV_ + j;
#pragma unroll
      for (int t = 0; t < 64; ++t) up[(size_t)t * VALD] = f2bf(m[t]);
    } else {
      int d = j - 192;
      u16* wp = Wg + (size_t)bT0 * KEYD + h * DK_ + d;
#pragma unroll
      for (int t = 0; t < 64; ++t) wp[(size_t)t * KEYD] = f2bf(m[t]);
    }
  }
}

// serial: per (bh, jq of DV/8): S_{c+1} = lam*S + K'^T E, E = U - W S.
__global__ __launch_bounds__(256) void serial_state(
    const u16* __restrict__ kc, const u16* __restrict__ Wg, u16* __restrict__ Ue,
    const float* __restrict__ cdArr, const float* __restrict__ lamArr,
    u16* __restrict__ Schk) {
  __shared__ u16 WtL[64 * 104];
  __shared__ u16 ktL[64 * 104];
  __shared__ float Sl[96 * 24];
  __shared__ float ElL[64 * 24];
  __shared__ float cdl[64];
  __shared__ float lamS;
  int tid = threadIdx.x;
  int jq = blockIdx.x & 7, bh = blockIdx.x >> 3, h = bh & 15, b = bh >> 4;
  for (int i = tid; i < 96 * 24; i += 256) Sl[i] = 0.f;

  for (int c = 0; c < NC_; ++c) {
    int flat = bh * NC_ + c;
    int bT0 = b * T_ + c * 64;
    __syncthreads();
    {
      const u32* wg = (const u32*)(Wg + (size_t)bT0 * KEYD + h * DK_);
      const u32* kg = (const u32*)(kc + (size_t)bT0 * KEYD + h * DK_);
      for (int i = tid; i < 3072; i += 256) {
        int t = i / 48, dd = i - t * 48;
        ((u32*)WtL)[t * 52 + dd] = wg[(size_t)t * (KEYD / 2) + dd];
        ((u32*)ktL)[t * 52 + dd] = kg[(size_t)t * (KEYD / 2) + dd];
      }
      if (tid < 64) cdl[tid] = cdArr[(size_t)flat * 64 + tid];
      if (tid == 0) lamS = lamArr[flat];
      for (int i = tid; i < 2304; i += 256) {
        int d = i / 24, jl = i - d * 24;
        Schk[((size_t)flat * DK_ + d) * DV_ + jq * 24 + jl] = f2bf(Sl[i]);
      }
    }
    __syncthreads();
    {
      int t = tid >> 2, jg = tid & 3;
      size_t gbase = (size_t)(bT0 + t) * VALD + h * DV_ + jq * 24 + jg * 6;
      const u32* up32 = (const u32*)(Ue + gbase);
      u32 u0 = up32[0], u1 = up32[1], u2 = up32[2];
      float ac[6] = {bflo(u0), bfhi(u0), bflo(u1), bfhi(u1), bflo(u2), bfhi(u2)};
#pragma unroll
      for (int dd8 = 0; dd8 < 12; ++dd8) {
        uint4 wv = *(const uint4*)((const char*)WtL + t * 208 + dd8 * 16);
        float wf[8]; up8(wv, wf);
#pragma unroll
        for (int e = 0; e < 8; ++e) {
          int d = dd8 * 8 + e;
          const float2* sp = (const float2*)&Sl[d * 24 + jg * 6];
          float2 s0 = sp[0], s1 = sp[1], s2 = sp[2];
          ac[0] -= wf[e] * s0.x; ac[1] -= wf[e] * s0.y; ac[2] -= wf[e] * s1.x;
          ac[3] -= wf[e] * s1.y; ac[4] -= wf[e] * s2.x; ac[5] -= wf[e] * s2.y;
        }
      }
      u32* ow = (u32*)(Ue + gbase);
      ow[0] = ((u32)f2bf(ac[1]) << 16) | f2bf(ac[0]);
      ow[1] = ((u32)f2bf(ac[3]) << 16) | f2bf(ac[2]);
      ow[2] = ((u32)f2bf(ac[5]) << 16) | f2bf(ac[4]);
      float cdv = cdl[t];
      float2* el = (float2*)&ElL[t * 24 + jg * 6];
      el[0] = make_float2(cdv * ac[0], cdv * ac[1]);
      el[1] = make_float2(cdv * ac[2], cdv * ac[3]);
      el[2] = make_float2(cdv * ac[4], cdv * ac[5]);
    }
    __syncthreads();
    float lamv = lamS;
#pragma unroll
    for (int r = 0; r < 2; ++r) {
      int unit = tid + 256 * r;
      if (unit < 384) {
        int d = unit >> 2, jg = unit & 3;
        float2* sp = (float2*)&Sl[d * 24 + jg * 6];
        float2 s0 = sp[0], s1 = sp[1], s2 = sp[2];
        float ac[6] = {lamv * s0.x, lamv * s0.y, lamv * s1.x,
                       lamv * s1.y, lamv * s2.x, lamv * s2.y};
#pragma unroll
        for (int t = 0; t < 64; ++t) {
          float kv = bf2f(ktL[t * 104 + d]);
          const float2* ep = (const float2*)&ElL[t * 24 + jg * 6];
          float2 e0 = ep[0], e1 = ep[1], e2 = ep[2];
          ac[0] += kv * e0.x; ac[1] += kv * e0.y; ac[2] += kv * e1.x;
          ac[3] += kv * e1.y; ac[4] += kv * e2.x; ac[5] += kv * e2.y;
        }
        sp[0] = make_float2(ac[0], ac[1]);
        sp[1] = make_float2(ac[2], ac[3]);
        sp[2] = make_float2(ac[4], ac[5]);
      }
    }
  }
}

// pass3 (MFMA): per (bh,chunk): O = diag(D)(Q S0) + tril_incl(Bm) E
// Bm[t,j] = exp(Gc_t-Gc_j) beta_j (q_t.k_j), stored bf16 hi+lo for precision.
__global__ __launch_bounds__(256) void chunk_out(
    const u16* __restrict__ qc, const u16* __restrict__ kc, const u16* __restrict__ Ee,
    const u16* __restrict__ Schk, const float* __restrict__ Gcum,
    const float* __restrict__ beta, u16* __restrict__ osc) {
  __shared__ __align__(16) char pool[65280];
  u16* qL   = (u16*)pool;              // [64][96]  = 12288
  u16* BmL  = (u16*)(pool + 12288);    // [64][72]  =  9216 -> 21504
  u16* BmLo = (u16*)(pool + 21504);    // [64][72]  =  9216 -> 30720
  u16* kL   = (u16*)(pool + 30720);    // [64][96]  = 12288 (phase A)
  u16* StL  = (u16*)(pool + 30720);    // [96][104] = 19968 (phase B) -> 50688
  u16* EtL  = (u16*)(pool + 50688);    // [96][72]  = 13824 -> 64512
  float* GclL = (float*)(pool + 64512);  // 256
  float* blL  = (float*)(pool + 64768);  // 256
  float* DlL  = (float*)(pool + 65024);  // 256 -> 65280

  int tid = threadIdx.x, wave = tid >> 6, lane = tid & 63;
  int l15 = lane & 15, l16 = lane >> 4;
  int flat = blockIdx.x;
  int c = flat & 31, bh = flat >> 5, h = bh & 15, b = bh >> 4;
  int bT0 = b * T_ + c * 64;

  // stage q,k row-major (48 u32 per row)
  {
    const u32* qg = (const u32*)(qc + (size_t)bT0 * KEYD + h * DK_);
    const u32* kg = (const u32*)(kc + (size_t)bT0 * KEYD + h * DK_);
    for (int i = tid; i < 3072; i += 256) {
      int t = i / 48, dd = i - t * 48;
      ((u32*)qL)[t * 48 + dd] = qg[(size_t)t * (KEYD / 2) + dd];
      ((u32*)kL)[t * 48 + dd] = kg[(size_t)t * (KEYD / 2) + dd];
    }
    if (tid < 64) {
      float gv = Gcum[(size_t)flat * 64 + tid];
      GclL[tid] = gv;
      DlL[tid] = __expf(gv);
      blL[tid] = beta[(size_t)(bT0 + tid) * H_ + h];
    }
  }
  __syncthreads();

  // Bm via MFMA: wave w computes rows 16w..16w+15 x cols 0..63
  {
    f32x4 bacc[4] = {};
#pragma unroll
    for (int kk = 0; kk < 3; ++kk) {
      bf16x8 aq = *(const bf16x8*)&qL[(wave * 16 + l15) * 96 + kk * 32 + l16 * 8];
#pragma unroll
      for (int n = 0; n < 4; ++n) {
        bf16x8 bk = *(const bf16x8*)&kL[(n * 16 + l15) * 96 + kk * 32 + l16 * 8];
        bacc[n] = __builtin_amdgcn_mfma_f32_16x16x32_bf16(aq, bk, bacc[n], 0, 0, 0);
      }
    }
#pragma unroll
    for (int n = 0; n < 4; ++n)
#pragma unroll
      for (int j = 0; j < 4; ++j) {
        int t = wave * 16 + l16 * 4 + j;
        int jj = n * 16 + l15;
        float val = 0.f;
        if (jj <= t) val = __expf(GclL[t] - GclL[jj]) * blL[jj] * bacc[n][j];
        u16 hi = f2bf(val);
        BmL[t * 72 + jj] = hi;
        BmLo[t * 72 + jj] = f2bf(val - bf2f(hi));
      }
  }
  __syncthreads();   // kL dead; StL/EtL may now overwrite it

#pragma unroll
  for (int half = 0; half < 2; ++half) {
    // stage S0^T (StL[c][d], c=0..95 within half) and E^T (EtL[c][t])
    {
      const u32* sg = (const u32*)(Schk + (size_t)flat * DK_ * DV_ + half * 96);
      for (int i = tid; i < 4608; i += 256) {
        int d = i / 48, dd = i - d * 48;
        u32 w2 = sg[(size_t)d * (DV_ / 2) + dd];
        StL[(2 * dd) * 104 + d]     = (u16)(w2 & 0xFFFF);
        StL[(2 * dd + 1) * 104 + d] = (u16)(w2 >> 16);
      }
      const u32* eg = (const u32*)(Ee + (size_t)bT0 * VALD + h * DV_ + half * 96);
      for (int i = tid; i < 3072; i += 256) {
        int t = i / 48, dd = i - t * 48;
        u32 w2 = eg[(size_t)t * (VALD / 2) + dd];
        EtL[(2 * dd) * 72 + t]     = (u16)(w2 & 0xFFFF);
        EtL[(2 * dd + 1) * 72 + t] = (u16)(w2 >> 16);
      }
    }
    __syncthreads();
    // wave w: rows 16w..16w+15, cols 0..95 of this half
    f32x4 oacc[6] = {};
#pragma unroll
    for (int kk = 0; kk < 3; ++kk) {
      bf16x8 aq = *(const bf16x8*)&qL[(wave * 16 + l15) * 96 + kk * 32 + l16 * 8];
#pragma unroll
      for (int n = 0; n < 6; ++n) {
        bf16x8 bs = *(const bf16x8*)&StL[(n * 16 + l15) * 104 + kk * 32 + l16 * 8];
        oacc[n] = __builtin_amdgcn_mfma_f32_16x16x32_bf16(aq, bs, oacc[n], 0, 0, 0);
      }
    }
#pragma unroll
    for (int n = 0; n < 6; ++n)
#pragma unroll
      for (int j = 0; j < 4; ++j)
        oacc[n][j] *= DlL[wave * 16 + l16 * 4 + j];
#pragma unroll
    for (int kk = 0; kk < 2; ++kk) {
      bf16x8 ah = *(const bf16x8*)&BmL[(wave * 16 + l15) * 72 + kk * 32 + l16 * 8];
      bf16x8 al = *(const bf16x8*)&BmLo[(wave * 16 + l15) * 72 + kk * 32 + l16 * 8];
#pragma unroll
      for (int n = 0; n < 6; ++n) {
        bf16x8 be = *(const bf16x8*)&EtL[(n * 16 + l15) * 72 + kk * 32 + l16 * 8];
        oacc[n] = __builtin_amdgcn_mfma_f32_16x16x32_bf16(ah, be, oacc[n], 0, 0, 0);
        oacc[n] = __builtin_amdgcn_mfma_f32_16x16x32_bf16(al, be, oacc[n], 0, 0, 0);
      }
    }
#pragma unroll
    for (int n = 0; n < 6; ++n)
#pragma unroll
      for (int j = 0; j < 4; ++j) {
        int t = wave * 16 + l16 * 4 + j;
        int cc = half * 96 + n * 16 + l15;
        osc[(size_t)(bT0 + t) * VALD + h * DV_ + cc] = f2bf(oacc[n][j]);
      }
    __syncthreads();   // St/Et reads done before restage
  }
}

// ---------- gated RMSNorm -> bf16 ----------
__global__ __launch_bounds__(256) void rmsnorm_gate(const u16* __restrict__ o,
    const u16* __restrict__ Pg, const float* __restrict__ w, u16* __restrict__ onb) {
  int bt = blockIdx.x;
  int tid = threadIdx.x, h = tid >> 4, li = tid & 15;
  const u16* orow = o + (size_t)bt * VALD + h * DV_;
  const u16* grow = Pg + (size_t)bt * VALD + h * DV_;
  float y[12]; float ss = 0.f;
#pragma unroll
  for (int jj = 0; jj < 12; ++jj) {
    float v = bf2f(orow[li + jj * 16]);
    y[jj] = v; ss += v * v;
  }
  ss += __shfl_xor(ss, 1); ss += __shfl_xor(ss, 2);
  ss += __shfl_xor(ss, 4); ss += __shfl_xor(ss, 8);
  float rms = rsqrtf(ss * (1.f / DV_) + 1e-6f);
  u16* out = onb + (size_t)bt * VALD + h * DV_;
#pragma unroll
  for (int jj = 0; jj < 12; ++jj) {
    int c = li + jj * 16;
    float gv = bf2f(grow[c]);
    float sig = 1.f / (1.f + __expf(-gv));
    out[c] = f2bf(y[jj] * rms * w[c] * sig);
  }
}

// ---------- launch ----------
extern "C" void kernel_launch(void* const* d_in, const int* in_sizes, int n_in,
                              void* d_out, int out_size, void* d_ws, size_t ws_size,
                              hipStream_t stream) {
  (void)in_sizes; (void)n_in; (void)out_size; (void)ws_size;
  const float* x      = (const float*)d_in[0];
  const float* Wq     = (const float*)d_in[1];
  const float* Wk     = (const float*)d_in[2];
  const float* Wv     = (const float*)d_in[3];
  const float* Wb     = (const float*)d_in[4];
  const float* Wa     = (const float*)d_in[5];
  const float* Wg     = (const float*)d_in[6];
  const float* Wo     = (const float*)d_in[7];
  const float* cqw    = (const float*)d_in[8];
  const float* ckw    = (const float*)d_in[9];
  const float* cvw    = (const float*)d_in[10];
  const float* A_log  = (const float*)d_in[11];
  const float* dt_bias= (const float*)d_in[12];
  const float* onw    = (const float*)d_in[13];
  float* out = (float*)d_out;

  char* ws = (char*)d_ws;
  u16*   xb    = (u16*)  (ws + 0);            // 16,777,216
  u16*   WT    = (u16*)  (ws + 16777216);     // 37,748,736
  u16*   qc    = (u16*)  (ws + 0);            // 12,582,912 (alias after gemm1)
  u16*   kc    = (u16*)  (ws + 12582912);     // 12,582,912
  u16*   vc    = (u16*)  (ws + 25165824);     // 25,165,824 (also U -> E, in place)
  u16*   Pqkv  = (u16*)  (ws + 54525952);     // 50,331,648
  u16*   Wbuf  = (u16*)  (ws + 54525952);     // 12,582,912 (alias after convs)
  u16*   Schk  = (u16*)  (ws + 67108864);     // 37,748,736
  u16*   Pg    = (u16*)  (ws + 104857600);    // 25,165,824
  u16*   osc   = (u16*)  (ws + 130023424);    // 25,165,824
  float* beta  = (float*)(ws + 155189248);    // 262,144
  float* gg    = (float*)(ws + 155451392);    // 262,144
  float* Gcum  = (float*)(ws + 155713536);    // 262,144
  float* cdArr = (float*)(ws + 155975680);    // 262,144
  float* lamArr= (float*)(ws + 156237824);    // 4,096  -> total 156,241,920
  u16*   onb   = (u16*)  (ws + 54525952);     // alias (after pass3)
  u16*   WoT   = (u16*)  (ws + 79691776);     // alias (after pass3)

  int n4 = B_ * T_ * D_ / 4;
  cast_x<<<(n4 + 255) / 256, 256, 0, stream>>>(x, xb, n4);
  transpose_cast<<<dim3(48, 64), 256, 0, stream>>>(Wq, WT, 2048, 1536);
  transpose_cast<<<dim3(48, 64), 256, 0, stream>>>(Wk, WT + (size_t)1536 * 2048, 2048, 1536);
  transpose_cast<<<dim3(96, 64), 256, 0, stream>>>(Wv, WT + (size_t)3072 * 2048, 2048, 3072);
  transpose_cast<<<dim3(96, 64), 256, 0, stream>>>(Wg, WT + (size_t)6144 * 2048, 2048, 3072);

  gemm_bt<1><<<dim3(NPROJ / 128, (B_ * T_) / 128), 256, 0, stream>>>(
      xb, WT, Pqkv, Pg, nullptr, B_ * T_, NPROJ, D_, PQK, PQK, VALD);
  proj_bg<<<(B_ * T_) / 4, 256, 0, stream>>>(x, Wb, Wa, A_log, dt_bias, beta, gg);
  conv_qk<<<B_ * T_, 256, 0, stream>>>(Pqkv, cqw, ckw, qc, kc);
  conv_v<<<(B_ * T_ * VALD) / 256, 256, 0, stream>>>(Pqkv, cvw, vc);

  chunk_prep<<<B_ * H_ * NC_, 320, 0, stream>>>(kc, vc, gg, beta, Wbuf, Gcum, cdArr, lamArr);
  serial_state<<<B_ * H_ * 8, 256, 0, stream>>>(kc, Wbuf, vc, cdArr, lamArr, Schk);
  chunk_out<<<B_ * H_ * NC_, 256, 0, stream>>>(qc, kc, vc, Schk, Gcum, beta, osc);

  rmsnorm_gate<<<B_ * T_, 256, 0, stream>>>(osc, Pg, onw, onb);
  transpose_cast<<<dim3(64, 96), 256, 0, stream>>>(Wo, WoT, 3072, 2048);
  gemm_bt<0><<<dim3(D_ / 128, (B_ * T_) / 128), 256, 0, stream>>>(
      onb, WoT, nullptr, nullptr, out, B_ * T_, D_, VALD, 0, 0, 0);
}

// Round 5
// 703.170 us; speedup vs baseline: 2.4988x; 1.4065x over previous
//
#include <hip/hip_runtime.h>

#define B_ 2
#define T_ 2048
#define D_ 2048
#define H_ 16
#define DK_ 96
#define DV_ 192
#define KEYD 1536
#define VALD 3072
#define NPROJ 9216
#define PQK 6144     // Pqkv row width (q|k|v)
#define KS_ 4
#define C_ 64
#define NC_ 32       // T_/C_

typedef unsigned short u16;
typedef unsigned int u32;
typedef __bf16 bf16x8 __attribute__((ext_vector_type(8)));
typedef float f32x4 __attribute__((ext_vector_type(4)));

// ---------- helpers ----------
__device__ __forceinline__ u16 f2bf(float f) {
  unsigned u = __float_as_uint(f);
  u += 0x7FFF + ((u >> 16) & 1);
  return (u16)(u >> 16);
}
__device__ __forceinline__ float bf2f(u16 v) { return __uint_as_float((unsigned)v << 16); }
__device__ __forceinline__ float bflo(u32 w) { return __uint_as_float(w << 16); }
__device__ __forceinline__ float bfhi(u32 w) { return __uint_as_float(w & 0xFFFF0000u); }
__device__ __forceinline__ void up8(uint4 u, float* f) {
  f[0]=bflo(u.x); f[1]=bfhi(u.x); f[2]=bflo(u.y); f[3]=bfhi(u.y);
  f[4]=bflo(u.z); f[5]=bfhi(u.z); f[6]=bflo(u.w); f[7]=bfhi(u.w);
}

__device__ __forceinline__ void gll16(const void* g, void* lds) {
  __builtin_amdgcn_global_load_lds(
      (const __attribute__((address_space(1))) void*)g,
      (__attribute__((address_space(3))) void*)lds, 16, 0, 0);
}

// ---------- casts / transposes ----------
__global__ __launch_bounds__(256) void cast_x(const float* __restrict__ in,
                                              u16* __restrict__ out, int n4) {
  int i = blockIdx.x * 256 + threadIdx.x;
  if (i < n4) {
    float4 v = reinterpret_cast<const float4*>(in)[i];
    ushort4 o;
    o.x = f2bf(v.x); o.y = f2bf(v.y); o.z = f2bf(v.z); o.w = f2bf(v.w);
    reinterpret_cast<ushort4*>(out)[i] = o;
  }
}

__global__ __launch_bounds__(256) void transpose_cast(const float* __restrict__ src,
                                                      u16* __restrict__ dst, int R, int C) {
  __shared__ float tile[32][33];
  int tx = threadIdx.x & 31, ty = threadIdx.x >> 5;
  int c0 = blockIdx.x * 32, r0 = blockIdx.y * 32;
#pragma unroll
  for (int j = 0; j < 4; ++j)
    tile[ty + j * 8][tx] = src[(size_t)(r0 + ty + j * 8) * C + c0 + tx];
  __syncthreads();
#pragma unroll
  for (int j = 0; j < 4; ++j)
    dst[(size_t)(c0 + ty + j * 8) * R + r0 + tx] = f2bf(tile[tx][ty + j * 8]);
}

// ---------- bf16 MFMA GEMM: C = A[M,K] * BT[N,K]^T ----------
template <int OUT16>
__global__ __launch_bounds__(256) void gemm_bt(const u16* __restrict__ A,
                                               const u16* __restrict__ BT,
                                               u16* __restrict__ C0, u16* __restrict__ C1,
                                               float* __restrict__ Cf,
                                               int M, int N, int K, int nsplit, int s0, int s1) {
  __shared__ u16 As[128 * 32];
  __shared__ u16 Bs[128 * 32];
  int tid = threadIdx.x;
  int wave = tid >> 6, lane = tid & 63;
  int l15 = lane & 15, l16 = lane >> 4;
  int m0 = blockIdx.y * 128, n0 = blockIdx.x * 128;
  int wm = (wave >> 1) * 64, wn = (wave & 1) * 64;
  f32x4 acc[4][4] = {};
  int nkt = K >> 5;
  for (int kt = 0; kt < nkt; ++kt) {
    int k0 = kt << 5;
    __syncthreads();
#pragma unroll
    for (int rr = 0; rr < 2; ++rr) {
      int idx = tid + rr * 256;
      int row = idx >> 2, kc8 = (idx & 3) * 8;
      unsigned loff = (unsigned)(rr * 256 + wave * 64) * 16;
      gll16(A + (size_t)(m0 + row) * K + k0 + kc8, (char*)As + loff);
      gll16(BT + (size_t)(n0 + row) * K + k0 + kc8, (char*)Bs + loff);
    }
    __syncthreads();
    bf16x8 af[4], bfr[4];
#pragma unroll
    for (int i = 0; i < 4; ++i)
      af[i] = *reinterpret_cast<const bf16x8*>(&As[(wm + i * 16 + l15) * 32 + l16 * 8]);
#pragma unroll
    for (int i = 0; i < 4; ++i)
      bfr[i] = *reinterpret_cast<const bf16x8*>(&Bs[(wn + i * 16 + l15) * 32 + l16 * 8]);
#pragma unroll
    for (int mi = 0; mi < 4; ++mi)
#pragma unroll
      for (int ni = 0; ni < 4; ++ni)
        acc[mi][ni] = __builtin_amdgcn_mfma_f32_16x16x32_bf16(af[mi], bfr[ni], acc[mi][ni], 0, 0, 0);
  }
#pragma unroll
  for (int mi = 0; mi < 4; ++mi)
#pragma unroll
    for (int ni = 0; ni < 4; ++ni)
#pragma unroll
      for (int j = 0; j < 4; ++j) {
        int row = m0 + wm + mi * 16 + l16 * 4 + j;
        int col = n0 + wn + ni * 16 + l15;
        if (OUT16) {
          if (col < nsplit) C0[(size_t)row * s0 + col] = f2bf(acc[mi][ni][j]);
          else              C1[(size_t)row * s1 + col - nsplit] = f2bf(acc[mi][ni][j]);
        } else {
          Cf[(size_t)row * N + col] = acc[mi][ni][j];
        }
      }
}

// ---------- beta / g projections ----------
__global__ __launch_bounds__(256) void proj_bg(const float* __restrict__ x,
    const float* __restrict__ Wb, const float* __restrict__ Wa,
    const float* __restrict__ A_log, const float* __restrict__ dt_bias,
    float* __restrict__ beta, float* __restrict__ gg) {
  __shared__ float xs[4 * 2048];
  __shared__ float red[4][32][8];
  int tid = threadIdx.x;
  int r0 = blockIdx.x * 4;
  for (int i = tid; i < 4 * 2048; i += 256)
    xs[i] = x[(size_t)r0 * D_ + i];
  __syncthreads();
  int colg = tid & 31, ks = tid >> 5;
  const float* W = (colg < 16) ? Wb : Wa;
  int wc = colg & 15;
  float p0 = 0, p1 = 0, p2 = 0, p3 = 0;
  int kbeg = ks * 256;
  for (int k = kbeg; k < kbeg + 256; ++k) {
    float wv = W[k * H_ + wc];
    p0 += xs[k] * wv;
    p1 += xs[2048 + k] * wv;
    p2 += xs[4096 + k] * wv;
    p3 += xs[6144 + k] * wv;
  }
  red[0][colg][ks] = p0; red[1][colg][ks] = p1;
  red[2][colg][ks] = p2; red[3][colg][ks] = p3;
  __syncthreads();
  if (tid < 128) {
    int row = tid >> 5, col = tid & 31;
    float d = 0;
#pragma unroll
    for (int i = 0; i < 8; ++i) d += red[row][col][i];
    int r = r0 + row;
    if (col < 16) {
      beta[(size_t)r * H_ + col] = 1.f / (1.f + __expf(-d));
    } else {
      int hh = col - 16;
      float z = d + dt_bias[hh];
      float sp = (z > 20.f) ? z : log1pf(__expf(z));
      gg[(size_t)r * H_ + hh] = -__expf(A_log[hh]) * sp;
    }
  }
}

// ---------- conv(KS=4)+SiLU+L2norm for q,k ----------
__global__ __launch_bounds__(256) void conv_qk(const u16* __restrict__ Pqkv,
    const float* __restrict__ wq, const float* __restrict__ wk,
    u16* __restrict__ qc, u16* __restrict__ kc) {
  int bt = blockIdx.x;
  int t = bt & (T_ - 1);
  int tid = threadIdx.x, h = tid >> 4, li = tid & 15;
#pragma unroll
  for (int part = 0; part < 2; ++part) {
    const float* w = part ? wk : wq;
    const u16* base = Pqkv + (size_t)bt * PQK + part * KEYD + h * DK_;
    float y[6]; float ss = 0.f;
#pragma unroll
    for (int jj = 0; jj < 6; ++jj) {
      int c = li + jj * 16;
      int ch = h * DK_ + c;
      float a = 0.f;
#pragma unroll
      for (int j = 0; j < KS_; ++j) {
        int dt = j - (KS_ - 1);
        if (t + dt >= 0) a += bf2f(base[(ptrdiff_t)dt * PQK + c]) * w[ch * KS_ + j];
      }
      float yv = a / (1.f + __expf(-a));
      y[jj] = yv; ss += yv * yv;
    }
    ss += __shfl_xor(ss, 1); ss += __shfl_xor(ss, 2);
    ss += __shfl_xor(ss, 4); ss += __shfl_xor(ss, 8);
    float rn = rsqrtf(ss + 1e-12f);
    u16* out = (part ? kc : qc) + (size_t)bt * KEYD + h * DK_;
#pragma unroll
    for (int jj = 0; jj < 6; ++jj) out[li + jj * 16] = f2bf(y[jj] * rn);
  }
}

// ---------- conv(KS=4)+SiLU for v ----------
__global__ __launch_bounds__(256) void conv_v(const u16* __restrict__ Pqkv,
    const float* __restrict__ wv, u16* __restrict__ vc) {
  int id = blockIdx.x * 256 + threadIdx.x;
  int bt = id / VALD, c = id - bt * VALD;
  int t = bt & (T_ - 1);
  const u16* base = Pqkv + (size_t)bt * PQK + 2 * KEYD + c;
  float a = 0.f;
#pragma unroll
  for (int j = 0; j < KS_; ++j) {
    int dt = j - (KS_ - 1);
    if (t + dt >= 0) a += bf2f(base[(ptrdiff_t)dt * PQK]) * wv[c * KS_ + j];
  }
  vc[id] = f2bf(a / (1.f + __expf(-a)));
}

// ================= chunked gated-delta scan =================
__global__ __launch_bounds__(320) void chunk_prep(
    const u16* __restrict__ kc, u16* __restrict__ Uv /* = vc, in-place */,
    const float* __restrict__ gg, const float* __restrict__ beta,
    u16* __restrict__ Wg, float* __restrict__ Gcum,
    float* __restrict__ cdArr, float* __restrict__ lamArr) {
  __shared__ u16 ktL[64 * 104];      // padded rows
  __shared__ float AmL[64 * 68];     // padded rows
  __shared__ float glL[64], GclL[64], blL[64], DplL[64];
  int tid = threadIdx.x;
  int flat = blockIdx.x;
  int c = flat & 31, bh = flat >> 5, h = bh & 15, b = bh >> 4;
  int bT0 = b * T_ + c * 64;

  {
    const u32* kg = (const u32*)(kc + (size_t)bT0 * KEYD + h * DK_);
    for (int i = tid; i < 3072; i += 320) {
      int t = i / 48, dd = i - t * 48;
      ((u32*)ktL)[t * 52 + dd] = kg[(size_t)t * (KEYD / 2) + dd];
    }
  }
  if (tid < 64) {
    float g = gg[(size_t)(bT0 + tid) * H_ + h];
    float bv = beta[(size_t)(bT0 + tid) * H_ + h];
    float v = g;
#pragma unroll
    for (int off = 1; off < 64; off <<= 1) {
      float u = __shfl_up(v, off);
      if (tid >= off) v += u;
    }
    float g63 = __shfl(v, 63);
    glL[tid] = g; GclL[tid] = v; blL[tid] = bv; DplL[tid] = __expf(v - g);
    Gcum[(size_t)flat * 64 + tid] = v;
    cdArr[(size_t)flat * 64 + tid] = bv * __expf(g63 - v);
    if (tid == 63) lamArr[flat] = __expf(v);
  }
  __syncthreads();

  if (tid < 256) {
    int tb = (tid >> 4) << 2, jb = (tid & 15) << 2;
    float a44[16];
#pragma unroll
    for (int i = 0; i < 16; ++i) a44[i] = 0.f;
    if (jb <= tb) {
#pragma unroll
      for (int dd8 = 0; dd8 < 12; ++dd8) {
        uint4 kr0 = *(const uint4*)((const char*)ktL + (tb + 0) * 208 + dd8 * 16);
        uint4 kr1 = *(const uint4*)((const char*)ktL + (tb + 1) * 208 + dd8 * 16);
        uint4 kr2 = *(const uint4*)((const char*)ktL + (tb + 2) * 208 + dd8 * 16);
        uint4 kr3 = *(const uint4*)((const char*)ktL + (tb + 3) * 208 + dd8 * 16);
        uint4 jr0 = *(const uint4*)((const char*)ktL + (jb + 0) * 208 + dd8 * 16);
        uint4 jr1 = *(const uint4*)((const char*)ktL + (jb + 1) * 208 + dd8 * 16);
        uint4 jr2 = *(const uint4*)((const char*)ktL + (jb + 2) * 208 + dd8 * 16);
        uint4 jr3 = *(const uint4*)((const char*)ktL + (jb + 3) * 208 + dd8 * 16);
        float kf0[8], kf1[8], kf2[8], kf3[8], jf0[8], jf1[8], jf2[8], jf3[8];
        up8(kr0, kf0); up8(kr1, kf1); up8(kr2, kf2); up8(kr3, kf3);
        up8(jr0, jf0); up8(jr1, jf1); up8(jr2, jf2); up8(jr3, jf3);
#pragma unroll
        for (int e = 0; e < 8; ++e) {
          a44[0]  += kf0[e] * jf0[e]; a44[1]  += kf0[e] * jf1[e];
          a44[2]  += kf0[e] * jf2[e]; a44[3]  += kf0[e] * jf3[e];
          a44[4]  += kf1[e] * jf0[e]; a44[5]  += kf1[e] * jf1[e];
          a44[6]  += kf1[e] * jf2[e]; a44[7]  += kf1[e] * jf3[e];
          a44[8]  += kf2[e] * jf0[e]; a44[9]  += kf2[e] * jf1[e];
          a44[10] += kf2[e] * jf2[e]; a44[11] += kf2[e] * jf3[e];
          a44[12] += kf3[e] * jf0[e]; a44[13] += kf3[e] * jf1[e];
          a44[14] += kf3[e] * jf2[e]; a44[15] += kf3[e] * jf3[e];
        }
      }
    }
#pragma unroll
    for (int r = 0; r < 4; ++r)
#pragma unroll
      for (int s = 0; s < 4; ++s) {
        int t = tb + r, j = jb + s;
        float val = 0.f;
        if (j < t) val = __expf((GclL[t] - glL[t]) - GclL[j]) * blL[j] * a44[r * 4 + s];
        AmL[t * 68 + j] = val;
      }
  }
  __syncthreads();

  if (tid < 288) {
    int j = tid;
    float m[64];
    if (j < 192) {
      const u16* up = Uv + (size_t)bT0 * VALD + h * DV_ + j;
#pragma unroll
      for (int t = 0; t < 64; ++t) m[t] = bf2f(up[(size_t)t * VALD]);
    } else {
      int d = j - 192;
#pragma unroll
      for (int t = 0; t < 64; ++t) m[t] = DplL[t] * bf2f(ktL[t * 104 + d]);
    }
#pragma unroll
    for (int t0 = 0; t0 < 64; t0 += 4) {
      {
        f32x4 a1 = *(const f32x4*)&AmL[(t0 + 1) * 68 + t0];
        m[t0 + 1] -= a1[0] * m[t0];
        f32x4 a2 = *(const f32x4*)&AmL[(t0 + 2) * 68 + t0];
        m[t0 + 2] -= a2[0] * m[t0] + a2[1] * m[t0 + 1];
        f32x4 a3 = *(const f32x4*)&AmL[(t0 + 3) * 68 + t0];
        m[t0 + 3] -= a3[0] * m[t0] + a3[1] * m[t0 + 1] + a3[2] * m[t0 + 2];
      }
#pragma unroll
      for (int tp = t0 + 4; tp < 64; ++tp) {
        f32x4 a = *(const f32x4*)&AmL[tp * 68 + t0];
        m[tp] -= a[0] * m[t0] + a[1] * m[t0 + 1] + a[2] * m[t0 + 2] + a[3] * m[t0 + 3];
      }
    }
    if (j < 192) {
      u16* up = Uv + (size_t)bT0 * VALD + h * DV_ + j;
#pragma unroll
      for (int t = 0; t < 64; ++t) up[(size_t)t * VALD] = f2bf(m[t]);
    } else {
      int d = j - 192;
      u16* wp = Wg + (size_t)bT0 * KEYD + h * DK_ + d;
#pragma unroll
      for (int t = 0; t < 64; ++t) wp[(size_t)t * KEYD] = f2bf(m[t]);
    }
  }
}

// serial (MFMA + prefetch): grid = (bh 32) x (jq 6, 32 cols each).
// Per chunk: E = U - W.S (MFMA, S as hi/lo bf16), E' = cd*E, S = lam*S + K^T.E' (MFMA).
// S stays f32 in C/D fragments across chunks; W/k/U/cd/lam prefetched one chunk ahead.
__global__ __launch_bounds__(256) void serial_state(
    const u16* __restrict__ kc, const u16* __restrict__ Wg, u16* __restrict__ Ue,
    const float* __restrict__ cdArr, const float* __restrict__ lamArr,
    u16* __restrict__ Schk) {
  __shared__ __align__(16) u16 WtL[2][64 * 104];   // W row-major, pad 104
  __shared__ __align__(16) u16 ktT[2][96 * 72];    // k^T [d][t], pad 72
  __shared__ __align__(16) u16 StH[32 * 104];      // S^T hi [col][d]
  __shared__ __align__(16) u16 StLo[32 * 104];     // S^T lo
  __shared__ __align__(16) u16 EtH[32 * 72];       // E'^T hi [col][t]
  __shared__ __align__(16) u16 EtLo[32 * 72];      // E'^T lo
  __shared__ float lamS[2];

  int tid = threadIdx.x, wave = tid >> 6, lane = tid & 63;
  int l15 = lane & 15, l16 = lane >> 4;
  int jq = blockIdx.x % 6, bh = blockIdx.x / 6, h = bh & 15, b = bh >> 4;
  int col0 = jq * 32;
  int ntS = wave & 1, m3 = 3 * (wave >> 1);        // S-frag tile assignment
  int st_t = tid >> 2, st_dd = (tid & 3) * 12;     // staging map (u32 units)

  f32x4 Sf[3] = {};
  uint4 wreg[3], kreg[3];
  u16 ureg[2][4];
  float cdv[4];
  float lamReg;

#define PREFETCH(bT0p, flatp) { \
    const u32* wgp = (const u32*)(Wg + (size_t)((bT0p) + st_t) * KEYD + h * DK_) + st_dd; \
    const u32* kgp = (const u32*)(kc + (size_t)((bT0p) + st_t) * KEYD + h * DK_) + st_dd; \
    wreg[0] = ((const uint4*)wgp)[0]; wreg[1] = ((const uint4*)wgp)[1]; wreg[2] = ((const uint4*)wgp)[2]; \
    kreg[0] = ((const uint4*)kgp)[0]; kreg[1] = ((const uint4*)kgp)[1]; kreg[2] = ((const uint4*)kgp)[2]; \
    _Pragma("unroll") \
    for (int ni = 0; ni < 2; ++ni) \
      _Pragma("unroll") \
      for (int j = 0; j < 4; ++j) \
        ureg[ni][j] = Ue[(size_t)((bT0p) + wave * 16 + l16 * 4 + j) * VALD + h * DV_ + col0 + ni * 16 + l15]; \
    _Pragma("unroll") \
    for (int j = 0; j < 4; ++j) cdv[j] = cdArr[(size_t)(flatp) * 64 + wave * 16 + l16 * 4 + j]; \
    if (tid == 0) lamReg = lamArr[flatp]; \
  }

  PREFETCH(b * T_, bh * NC_);

  for (int c = 0; c < NC_; ++c) {
    int buf = c & 1;
    int flat = bh * NC_ + c;
    int bT0 = b * T_ + (c << 6);
    // ---- phase A: commit prefetched tiles to LDS; publish S^T + Schk snapshot ----
    {
      u32* wl = (u32*)&WtL[buf][0] + st_t * 52 + st_dd;
      ((uint4*)wl)[0] = wreg[0];
      *(uint4*)(wl + 4) = wreg[1];
      *(uint4*)(wl + 8) = wreg[2];
#pragma unroll
      for (int r = 0; r < 3; ++r) {
        u32 vals[4] = {kreg[r].x, kreg[r].y, kreg[r].z, kreg[r].w};
#pragma unroll
        for (int e = 0; e < 4; ++e) {
          int d = 2 * (st_dd + r * 4 + e);
          ktT[buf][d * 72 + st_t] = (u16)(vals[e] & 0xFFFFu);
          ktT[buf][(d + 1) * 72 + st_t] = (u16)(vals[e] >> 16);
        }
      }
      int cl = ntS * 16 + l15;
#pragma unroll
      for (int i = 0; i < 3; ++i)
#pragma unroll
        for (int j = 0; j < 4; ++j) {
          float sv = Sf[i][j];
          int d = (m3 + i) * 16 + l16 * 4 + j;
          u16 hi = f2bf(sv);
          StH[cl * 104 + d] = hi;
          StLo[cl * 104 + d] = f2bf(sv - bf2f(hi));
          Schk[(size_t)flat * (DK_ * DV_) + (size_t)d * DV_ + col0 + cl] = hi;
        }
      if (tid == 0) lamS[buf] = lamReg;
    }
    __syncthreads();
    // ---- phase B: E-step (MFMA) + E store + E'^T publish + prefetch c+1 ----
    {
      f32x4 Ea[2] = {};
#pragma unroll
      for (int ks = 0; ks < 3; ++ks) {
        bf16x8 a = *(const bf16x8*)&WtL[buf][(wave * 16 + l15) * 104 + ks * 32 + l16 * 8];
#pragma unroll
        for (int ni = 0; ni < 2; ++ni) {
          bf16x8 bhv = *(const bf16x8*)&StH[(ni * 16 + l15) * 104 + ks * 32 + l16 * 8];
          bf16x8 blv = *(const bf16x8*)&StLo[(ni * 16 + l15) * 104 + ks * 32 + l16 * 8];
          Ea[ni] = __builtin_amdgcn_mfma_f32_16x16x32_bf16(a, bhv, Ea[ni], 0, 0, 0);
          Ea[ni] = __builtin_amdgcn_mfma_f32_16x16x32_bf16(a, blv, Ea[ni], 0, 0, 0);
        }
      }
#pragma unroll
      for (int ni = 0; ni < 2; ++ni)
#pragma unroll
        for (int j = 0; j < 4; ++j) {
          int t = wave * 16 + l16 * 4 + j;
          float ev = bf2f(ureg[ni][j]) - Ea[ni][j];
          Ue[(size_t)(bT0 + t) * VALD + h * DV_ + col0 + ni * 16 + l15] = f2bf(ev);
          float ep = cdv[j] * ev;
          u16 ehi = f2bf(ep);
          int cl = ni * 16 + l15;
          EtH[cl * 72 + t] = ehi;
          EtLo[cl * 72 + t] = f2bf(ep - bf2f(ehi));
        }
      if (c + 1 < NC_) PREFETCH(bT0 + 64, flat + 1);
    }
    __syncthreads();
    // ---- phase C: S-step (MFMA) ----
    {
      float lam = lamS[buf];
#pragma unroll
      for (int i = 0; i < 3; ++i)
#pragma unroll
        for (int j = 0; j < 4; ++j) Sf[i][j] *= lam;
#pragma unroll
      for (int ks = 0; ks < 2; ++ks) {
        bf16x8 bhv = *(const bf16x8*)&EtH[(ntS * 16 + l15) * 72 + ks * 32 + l16 * 8];
        bf16x8 blv = *(const bf16x8*)&EtLo[(ntS * 16 + l15) * 72 + ks * 32 + l16 * 8];
#pragma unroll
        for (int i = 0; i < 3; ++i) {
          bf16x8 a = *(const bf16x8*)&ktT[buf][((m3 + i) * 16 + l15) * 72 + ks * 32 + l16 * 8];
          Sf[i] = __builtin_amdgcn_mfma_f32_16x16x32_bf16(a, bhv, Sf[i], 0, 0, 0);
          Sf[i] = __builtin_amdgcn_mfma_f32_16x16x32_bf16(a, blv, Sf[i], 0, 0, 0);
        }
      }
    }
  }
#undef PREFETCH
}

// pass3 (MFMA): per (bh,chunk): O = diag(D)(Q S0) + tril_incl(Bm) E
__global__ __launch_bounds__(256) void chunk_out(
    const u16* __restrict__ qc, const u16* __restrict__ kc, const u16* __restrict__ Ee,
    const u16* __restrict__ Schk, const float* __restrict__ Gcum,
    const float* __restrict__ beta, u16* __restrict__ osc) {
  __shared__ __align__(16) char pool[65280];
  u16* qL   = (u16*)pool;              // [64][96]  = 12288
  u16* BmL  = (u16*)(pool + 12288);    // [64][72]  =  9216 -> 21504
  u16* BmLo = (u16*)(pool + 21504);    // [64][72]  =  9216 -> 30720
  u16* kL   = (u16*)(pool + 30720);    // [64][96]  = 12288 (phase A)
  u16* StL  = (u16*)(pool + 30720);    // [96][104] = 19968 (phase B) -> 50688
  u16* EtL  = (u16*)(pool + 50688);    // [96][72]  = 13824 -> 64512
  float* GclL = (float*)(pool + 64512);  // 256
  float* blL  = (float*)(pool + 64768);  // 256
  float* DlL  = (float*)(pool + 65024);  // 256 -> 65280

  int tid = threadIdx.x, wave = tid >> 6, lane = tid & 63;
  int l15 = lane & 15, l16 = lane >> 4;
  int flat = blockIdx.x;
  int c = flat & 31, bh = flat >> 5, h = bh & 15, b = bh >> 4;
  int bT0 = b * T_ + c * 64;

  {
    const u32* qg = (const u32*)(qc + (size_t)bT0 * KEYD + h * DK_);
    const u32* kg = (const u32*)(kc + (size_t)bT0 * KEYD + h * DK_);
    for (int i = tid; i < 3072; i += 256) {
      int t = i / 48, dd = i - t * 48;
      ((u32*)qL)[t * 48 + dd] = qg[(size_t)t * (KEYD / 2) + dd];
      ((u32*)kL)[t * 48 + dd] = kg[(size_t)t * (KEYD / 2) + dd];
    }
    if (tid < 64) {
      float gv = Gcum[(size_t)flat * 64 + tid];
      GclL[tid] = gv;
      DlL[tid] = __expf(gv);
      blL[tid] = beta[(size_t)(bT0 + tid) * H_ + h];
    }
  }
  __syncthreads();

  {
    f32x4 bacc[4] = {};
#pragma unroll
    for (int kk = 0; kk < 3; ++kk) {
      bf16x8 aq = *(const bf16x8*)&qL[(wave * 16 + l15) * 96 + kk * 32 + l16 * 8];
#pragma unroll
      for (int n = 0; n < 4; ++n) {
        bf16x8 bk = *(const bf16x8*)&kL[(n * 16 + l15) * 96 + kk * 32 + l16 * 8];
        bacc[n] = __builtin_amdgcn_mfma_f32_16x16x32_bf16(aq, bk, bacc[n], 0, 0, 0);
      }
    }
#pragma unroll
    for (int n = 0; n < 4; ++n)
#pragma unroll
      for (int j = 0; j < 4; ++j) {
        int t = wave * 16 + l16 * 4 + j;
        int jj = n * 16 + l15;
        float val = 0.f;
        if (jj <= t) val = __expf(GclL[t] - GclL[jj]) * blL[jj] * bacc[n][j];
        u16 hi = f2bf(val);
        BmL[t * 72 + jj] = hi;
        BmLo[t * 72 + jj] = f2bf(val - bf2f(hi));
      }
  }
  __syncthreads();   // kL dead; StL/EtL may now overwrite it

#pragma unroll
  for (int half = 0; half < 2; ++half) {
    {
      const u32* sg = (const u32*)(Schk + (size_t)flat * DK_ * DV_ + half * 96);
      for (int i = tid; i < 4608; i += 256) {
        int d = i / 48, dd = i - d * 48;
        u32 w2 = sg[(size_t)d * (DV_ / 2) + dd];
        StL[(2 * dd) * 104 + d]     = (u16)(w2 & 0xFFFF);
        StL[(2 * dd + 1) * 104 + d] = (u16)(w2 >> 16);
      }
      const u32* eg = (const u32*)(Ee + (size_t)bT0 * VALD + h * DV_ + half * 96);
      for (int i = tid; i < 3072; i += 256) {
        int t = i / 48, dd = i - t * 48;
        u32 w2 = eg[(size_t)t * (VALD / 2) + dd];
        EtL[(2 * dd) * 72 + t]     = (u16)(w2 & 0xFFFF);
        EtL[(2 * dd + 1) * 72 + t] = (u16)(w2 >> 16);
      }
    }
    __syncthreads();
    f32x4 oacc[6] = {};
#pragma unroll
    for (int kk = 0; kk < 3; ++kk) {
      bf16x8 aq = *(const bf16x8*)&qL[(wave * 16 + l15) * 96 + kk * 32 + l16 * 8];
#pragma unroll
      for (int n = 0; n < 6; ++n) {
        bf16x8 bs = *(const bf16x8*)&StL[(n * 16 + l15) * 104 + kk * 32 + l16 * 8];
        oacc[n] = __builtin_amdgcn_mfma_f32_16x16x32_bf16(aq, bs, oacc[n], 0, 0, 0);
      }
    }
#pragma unroll
    for (int n = 0; n < 6; ++n)
#pragma unroll
      for (int j = 0; j < 4; ++j)
        oacc[n][j] *= DlL[wave * 16 + l16 * 4 + j];
#pragma unroll
    for (int kk = 0; kk < 2; ++kk) {
      bf16x8 ah = *(const bf16x8*)&BmL[(wave * 16 + l15) * 72 + kk * 32 + l16 * 8];
      bf16x8 al = *(const bf16x8*)&BmLo[(wave * 16 + l15) * 72 + kk * 32 + l16 * 8];
#pragma unroll
      for (int n = 0; n < 6; ++n) {
        bf16x8 be = *(const bf16x8*)&EtL[(n * 16 + l15) * 72 + kk * 32 + l16 * 8];
        oacc[n] = __builtin_amdgcn_mfma_f32_16x16x32_bf16(ah, be, oacc[n], 0, 0, 0);
        oacc[n] = __builtin_amdgcn_mfma_f32_16x16x32_bf16(al, be, oacc[n], 0, 0, 0);
      }
    }
#pragma unroll
    for (int n = 0; n < 6; ++n)
#pragma unroll
      for (int j = 0; j < 4; ++j) {
        int t = wave * 16 + l16 * 4 + j;
        int cc = half * 96 + n * 16 + l15;
        osc[(size_t)(bT0 + t) * VALD + h * DV_ + cc] = f2bf(oacc[n][j]);
      }
    __syncthreads();
  }
}

// ---------- gated RMSNorm -> bf16 ----------
__global__ __launch_bounds__(256) void rmsnorm_gate(const u16* __restrict__ o,
    const u16* __restrict__ Pg, const float* __restrict__ w, u16* __restrict__ onb) {
  int bt = blockIdx.x;
  int tid = threadIdx.x, h = tid >> 4, li = tid & 15;
  const u16* orow = o + (size_t)bt * VALD + h * DV_;
  const u16* grow = Pg + (size_t)bt * VALD + h * DV_;
  float y[12]; float ss = 0.f;
#pragma unroll
  for (int jj = 0; jj < 12; ++jj) {
    float v = bf2f(orow[li + jj * 16]);
    y[jj] = v; ss += v * v;
  }
  ss += __shfl_xor(ss, 1); ss += __shfl_xor(ss, 2);
  ss += __shfl_xor(ss, 4); ss += __shfl_xor(ss, 8);
  float rms = rsqrtf(ss * (1.f / DV_) + 1e-6f);
  u16* out = onb + (size_t)bt * VALD + h * DV_;
#pragma unroll
  for (int jj = 0; jj < 12; ++jj) {
    int c = li + jj * 16;
    float gv = bf2f(grow[c]);
    float sig = 1.f / (1.f + __expf(-gv));
    out[c] = f2bf(y[jj] * rms * w[c] * sig);
  }
}

// ---------- launch ----------
extern "C" void kernel_launch(void* const* d_in, const int* in_sizes, int n_in,
                              void* d_out, int out_size, void* d_ws, size_t ws_size,
                              hipStream_t stream) {
  (void)in_sizes; (void)n_in; (void)out_size; (void)ws_size;
  const float* x      = (const float*)d_in[0];
  const float* Wq     = (const float*)d_in[1];
  const float* Wk     = (const float*)d_in[2];
  const float* Wv     = (const float*)d_in[3];
  const float* Wb     = (const float*)d_in[4];
  const float* Wa     = (const float*)d_in[5];
  const float* Wg     = (const float*)d_in[6];
  const float* Wo     = (const float*)d_in[7];
  const float* cqw    = (const float*)d_in[8];
  const float* ckw    = (const float*)d_in[9];
  const float* cvw    = (const float*)d_in[10];
  const float* A_log  = (const float*)d_in[11];
  const float* dt_bias= (const float*)d_in[12];
  const float* onw    = (const float*)d_in[13];
  float* out = (float*)d_out;

  char* ws = (char*)d_ws;
  u16*   xb    = (u16*)  (ws + 0);            // 16,777,216
  u16*   WT    = (u16*)  (ws + 16777216);     // 37,748,736
  u16*   qc    = (u16*)  (ws + 0);            // 12,582,912 (alias after gemm1)
  u16*   kc    = (u16*)  (ws + 12582912);     // 12,582,912
  u16*   vc    = (u16*)  (ws + 25165824);     // 25,165,824 (also U -> E, in place)
  u16*   Pqkv  = (u16*)  (ws + 54525952);     // 50,331,648
  u16*   Wbuf  = (u16*)  (ws + 54525952);     // 12,582,912 (alias after convs)
  u16*   Schk  = (u16*)  (ws + 67108864);     // 37,748,736
  u16*   Pg    = (u16*)  (ws + 104857600);    // 25,165,824
  u16*   osc   = (u16*)  (ws + 130023424);    // 25,165,824
  float* beta  = (float*)(ws + 155189248);    // 262,144
  float* gg    = (float*)(ws + 155451392);    // 262,144
  float* Gcum  = (float*)(ws + 155713536);    // 262,144
  float* cdArr = (float*)(ws + 155975680);    // 262,144
  float* lamArr= (float*)(ws + 156237824);    // 4,096  -> total 156,241,920
  u16*   onb   = (u16*)  (ws + 54525952);     // alias (after pass3)
  u16*   WoT   = (u16*)  (ws + 79691776);     // alias (after pass3)

  int n4 = B_ * T_ * D_ / 4;
  cast_x<<<(n4 + 255) / 256, 256, 0, stream>>>(x, xb, n4);
  transpose_cast<<<dim3(48, 64), 256, 0, stream>>>(Wq, WT, 2048, 1536);
  transpose_cast<<<dim3(48, 64), 256, 0, stream>>>(Wk, WT + (size_t)1536 * 2048, 2048, 1536);
  transpose_cast<<<dim3(96, 64), 256, 0, stream>>>(Wv, WT + (size_t)3072 * 2048, 2048, 3072);
  transpose_cast<<<dim3(96, 64), 256, 0, stream>>>(Wg, WT + (size_t)6144 * 2048, 2048, 3072);

  gemm_bt<1><<<dim3(NPROJ / 128, (B_ * T_) / 128), 256, 0, stream>>>(
      xb, WT, Pqkv, Pg, nullptr, B_ * T_, NPROJ, D_, PQK, PQK, VALD);
  proj_bg<<<(B_ * T_) / 4, 256, 0, stream>>>(x, Wb, Wa, A_log, dt_bias, beta, gg);
  conv_qk<<<B_ * T_, 256, 0, stream>>>(Pqkv, cqw, ckw, qc, kc);
  conv_v<<<(B_ * T_ * VALD) / 256, 256, 0, stream>>>(Pqkv, cvw, vc);

  chunk_prep<<<B_ * H_ * NC_, 320, 0, stream>>>(kc, vc, gg, beta, Wbuf, Gcum, cdArr, lamArr);
  serial_state<<<B_ * H_ * 6, 256, 0, stream>>>(kc, Wbuf, vc, cdArr, lamArr, Schk);
  chunk_out<<<B_ * H_ * NC_, 256, 0, stream>>>(qc, kc, vc, Schk, Gcum, beta, osc);

  rmsnorm_gate<<<B_ * T_, 256, 0, stream>>>(osc, Pg, onw, onb);
  transpose_cast<<<dim3(64, 96), 256, 0, stream>>>(Wo, WoT, 3072, 2048);
  gemm_bt<0><<<dim3(D_ / 128, (B_ * T_) / 128), 256, 0, stream>>>(
      onb, WoT, nullptr, nullptr, out, B_ * T_, D_, VALD, 0, 0, 0);
}